// Round 11
// baseline (1223.548 us; speedup 1.0000x reference)
//
#include <hip/hip_runtime.h>

// HierarchicalResidualQuantizer on gfx950 — numpy-fp32-exact decision path.
// N=16384 tokens, D=256, L=8 levels, K=512 codes.
// Outputs (flat fp32 in d_out): q_out[16,256,32,32] @0, indices[16,32,32,8] @4194304,
// loss[16] @4325376, all_probs[16384,8,512] @4325392.  Total 71,434,256 floats.
// Scratch lives in the TAIL of the probs region.
//
// R18 (on R17's 1222us):
// (1) k_level Phase E: float4 loads for w and z (4x fewer load instructions),
//     16-element groups, #pragma unroll 2 (small live window — R14's deep
//     version regressed via +128 VGPR). fmaf order over j=0..255 IDENTICAL
//     (elementwise x,y,z,w ascending) -> bit-identical c / argmax.
// (2) k_out1 q_out gather: float4 w loads (512 -> 128 loads/thread); per-d
//     sum order over l unchanged.
// Carried: Phase-A hoist via ACCS (T=64 in gsum/prep), T=16 k_level grid 1024,
// gsum probs piggyback, merged prep, R13 epilogue ordering.

typedef _Float16 f16;
typedef _Float16 half8 __attribute__((ext_vector_type(8)));
typedef _Float16 half4v __attribute__((ext_vector_type(4)));
typedef float f32x4 __attribute__((ext_vector_type(4)));

#define LOGK 6.238324625039508f

#define OUT_IDX 4194304
#define OUT_LOSS 4325376
#define OUT_PROBS 4325392

#define SCR_FLOATS 13915408
// scratch offsets in floats
#define SF_ZH 0              // f16[16384*256]
#define SF_ZL 2097152        // f16[16384*256]
#define SF_WH 4194304        // f16[4096*256]
#define SF_WL 4718592        // f16[4096*256]
#define SF_B32 5242880       // float[4096]  fp32 pairwise ||w||^2 (numpy-exact)
#define SF_G32 5246976       // float[256]   fp32 global_sum (numpy-exact bits)
#define SF_G2D 5247232       // double[512]  2*g.w_k for next level
#define SF_IDX 5248256       // int[16384*8]
#define SF_IDXL 5379328      // int[8*16384] level-major indices
#define SF_KL 5510400        // float[16384]
#define SF_DONE 5526784      // int[1] cross-block counter (+pad)
#define SF_ACC 5526800       // float[16384*512] Phase-A scores for current level

// ---------- numpy pairwise-128 block: 8 accumulators + fixed combine tree ----------
__device__ __forceinline__ float np_combine8(const float r[8]) {
    return __fadd_rn(__fadd_rn(__fadd_rn(r[0], r[1]), __fadd_rn(r[2], r[3])),
                     __fadd_rn(__fadd_rn(r[4], r[5]), __fadd_rn(r[6], r[7])));
}

// hi/lo fp16 split of 8 scaled floats — identical arithmetic to prep's split.
__device__ __forceinline__ void cvt8(const float* p, float sc, half8& h, half8& l) {
    #pragma unroll
    for (int j = 0; j < 8; ++j) {
        float v = p[j] * sc;
        f16 hh = (f16)v;
        h[j] = hh;
        l[j] = (f16)(v - (float)hh);
    }
}

// Phase A, T=64 tokens / 256 threads (4 waves), two code-passes of 256 codes.
// Per pass: wave owns 64 codes (nt=0..3), sweeps 4 token groups. MFMA order
// per (token,code): per k0 ascending, (hi*bh, hi*bl, lo*bh) — R8-exact.
__device__ __forceinline__ void phaseA64(
        int tid, int tok0, int lvl, float* __restrict__ accS,
        const f16* __restrict__ zh, const f16* __restrict__ zl,
        const f16* __restrict__ wh, const f16* __restrict__ wl) {
    const int wave = tid >> 6, lane = tid & 63;
    const int quad = lane >> 4, lr = lane & 15;
    #pragma unroll
    for (int cp = 0; cp < 2; ++cp) {
        const int code0 = cp * 256 + wave * 64;
        const f16* za = zh + (tok0 + lr) * 256 + quad * 8;
        const f16* zb = zl + (tok0 + lr) * 256 + quad * 8;
        const f16* wa = wh + (lvl * 512 + code0 + lr) * 256 + quad * 8;
        const f16* wb = wl + (lvl * 512 + code0 + lr) * 256 + quad * 8;
        f32x4 acc[4][4];
        #pragma unroll
        for (int g = 0; g < 4; ++g)
            #pragma unroll
            for (int nt = 0; nt < 4; ++nt)
                acc[g][nt] = (f32x4){0.f, 0.f, 0.f, 0.f};
        for (int k0 = 0; k0 < 256; k0 += 32) {
            half8 ah[4], al[4];
            #pragma unroll
            for (int g = 0; g < 4; ++g) {
                ah[g] = *(const half8*)(za + g * 16 * 256 + k0);
                al[g] = *(const half8*)(zb + g * 16 * 256 + k0);
            }
            half8 bh[4], bl[4];
            #pragma unroll
            for (int nt = 0; nt < 4; ++nt) {
                bh[nt] = *(const half8*)(wa + nt * 16 * 256 + k0);
                bl[nt] = *(const half8*)(wb + nt * 16 * 256 + k0);
            }
            #pragma unroll
            for (int nt = 0; nt < 4; ++nt)
                #pragma unroll
                for (int g = 0; g < 4; ++g) {
                    acc[g][nt] = __builtin_amdgcn_mfma_f32_16x16x32_f16(ah[g], bh[nt], acc[g][nt], 0, 0, 0);
                    acc[g][nt] = __builtin_amdgcn_mfma_f32_16x16x32_f16(ah[g], bl[nt], acc[g][nt], 0, 0, 0);
                    acc[g][nt] = __builtin_amdgcn_mfma_f32_16x16x32_f16(al[g], bh[nt], acc[g][nt], 0, 0, 0);
                }
        }
        #pragma unroll
        for (int g = 0; g < 4; ++g)
            #pragma unroll
            for (int r = 0; r < 4; ++r) {
                int token = tok0 + g * 16 + quad * 4 + r;
                float* dst = accS + (size_t)token * 512 + code0 + lr;
                #pragma unroll
                for (int nt = 0; nt < 4; ++nt)
                    dst[nt * 16] = acc[g][nt][r];
            }
    }
}

// fp32-direct Phase A T=64 (level 0, inside prep): identical split arithmetic.
__device__ __forceinline__ void phaseA64_f32(
        int tid, int tok0, float* __restrict__ accS,
        const float* __restrict__ z, const float* __restrict__ w) {
    const int wave = tid >> 6, lane = tid & 63;
    const int quad = lane >> 4, lr = lane & 15;
    const float sc = 16.0f;                                    // 1<<(0+4)
    #pragma unroll
    for (int cp = 0; cp < 2; ++cp) {
        const int code0 = cp * 256 + wave * 64;
        const float* zr = z + (tok0 + lr) * 256 + quad * 8;
        const float* wr = w + (code0 + lr) * 256 + quad * 8;   // lvl 0
        f32x4 acc[4][4];
        #pragma unroll
        for (int g = 0; g < 4; ++g)
            #pragma unroll
            for (int nt = 0; nt < 4; ++nt)
                acc[g][nt] = (f32x4){0.f, 0.f, 0.f, 0.f};
        for (int k0 = 0; k0 < 256; k0 += 32) {
            half8 ah[4], al[4];
            #pragma unroll
            for (int g = 0; g < 4; ++g)
                cvt8(zr + g * 16 * 256 + k0, 1.0f, ah[g], al[g]);
            half8 bh[4], bl[4];
            #pragma unroll
            for (int nt = 0; nt < 4; ++nt)
                cvt8(wr + nt * 16 * 256 + k0, sc, bh[nt], bl[nt]);
            #pragma unroll
            for (int nt = 0; nt < 4; ++nt)
                #pragma unroll
                for (int g = 0; g < 4; ++g) {
                    acc[g][nt] = __builtin_amdgcn_mfma_f32_16x16x32_f16(ah[g], bh[nt], acc[g][nt], 0, 0, 0);
                    acc[g][nt] = __builtin_amdgcn_mfma_f32_16x16x32_f16(ah[g], bl[nt], acc[g][nt], 0, 0, 0);
                    acc[g][nt] = __builtin_amdgcn_mfma_f32_16x16x32_f16(al[g], bh[nt], acc[g][nt], 0, 0, 0);
                }
        }
        #pragma unroll
        for (int g = 0; g < 4; ++g)
            #pragma unroll
            for (int r = 0; r < 4; ++r) {
                int token = tok0 + g * 16 + quad * 4 + r;
                float* dst = accS + (size_t)token * 512 + code0 + lr;
                #pragma unroll
                for (int nt = 0; nt < 4; ++nt)
                    dst[nt * 16] = acc[g][nt][r];
            }
    }
}

// Fused prep: [0,4096) z hi/lo split, [4096,5120) w hi/lo split,
// [5120,5136) ||w||^2 + misc init, [5136,5392) Phase A level 0 (fp32-direct, T=64).
__global__ __launch_bounds__(256) void k_prep(
        const float* __restrict__ z, const float* __restrict__ w,
        f16* __restrict__ zh, f16* __restrict__ zl,
        f16* __restrict__ wh, f16* __restrict__ wl,
        float* __restrict__ b32, float* __restrict__ g32,
        double* __restrict__ G2, float* __restrict__ loss_out,
        int* __restrict__ done, float* __restrict__ accS) {
    const int bid = blockIdx.x;
    const int tid = threadIdx.x;
    if (bid < 4096) {
        int i = (bid * 256 + tid) * 4;
        float4 v = *(const float4*)(z + i);
        half4v h, l;
        float c0 = v.x, c1 = v.y, c2 = v.z, c3 = v.w;
        f16 h0 = (f16)c0, h1 = (f16)c1, h2 = (f16)c2, h3 = (f16)c3;
        h[0] = h0; h[1] = h1; h[2] = h2; h[3] = h3;
        l[0] = (f16)(c0 - (float)h0); l[1] = (f16)(c1 - (float)h1);
        l[2] = (f16)(c2 - (float)h2); l[3] = (f16)(c3 - (float)h3);
        *(half4v*)(zh + i) = h;
        *(half4v*)(zl + i) = l;
    } else if (bid < 5120) {
        int row = (bid - 4096) * 4 + (tid >> 6);
        int lane = tid & 63;
        int lvl = row >> 9;
        float sc = (float)(1 << (lvl + 4));
        const float* wr = w + row * 256;
        int d0 = lane * 4;
        float4 v = *(const float4*)(wr + d0);
        half4v h, l;
        float s0 = v.x * sc, s1 = v.y * sc, s2 = v.z * sc, s3 = v.w * sc;
        f16 h0 = (f16)s0, h1 = (f16)s1, h2 = (f16)s2, h3 = (f16)s3;
        h[0] = h0; h[1] = h1; h[2] = h2; h[3] = h3;
        l[0] = (f16)(s0 - (float)h0); l[1] = (f16)(s1 - (float)h1);
        l[2] = (f16)(s2 - (float)h2); l[3] = (f16)(s3 - (float)h3);
        *(half4v*)(wh + row * 256 + d0) = h;
        *(half4v*)(wl + row * 256 + d0) = l;
    } else if (bid < 5136) {
        int b = bid - 5120;                 // 0..15
        int row = b * 256 + tid;            // 0..4095
        const float* wr = w + row * 256;
        float res[2];
        #pragma unroll
        for (int h = 0; h < 2; ++h) {
            const float* x = wr + h * 128;
            float r[8];
            #pragma unroll
            for (int j = 0; j < 8; ++j) r[j] = __fmul_rn(x[j], x[j]);
            for (int i = 8; i < 128; i += 8)
                #pragma unroll
                for (int j = 0; j < 8; ++j) r[j] = __fadd_rn(r[j], __fmul_rn(x[i + j], x[i + j]));
            res[h] = np_combine8(r);
        }
        b32[row] = __fadd_rn(res[0], res[1]);
        if (b == 0) {
            g32[tid] = 0.0f;
            G2[tid] = 0.0; G2[tid + 256] = 0.0;
            if (tid < 16) loss_out[tid] = 0.0f;
            if (tid == 0) *done = 0;
        }
    } else {
        int tok0 = (bid - 5136) * 64;
        phaseA64_f32(tid, tok0, accS, z, w);
    }
}

// Per-level, 16 tokens/block, 256 threads, grid 1024 (4 blocks/CU, 4 waves/SIMD).
// Phase A is PRE-COMPUTED in ACCS. B (R12-validated 16-thread split) ->
// C/C2 (thread owns 32 codes of its token) -> KL -> E (float4 loads, exact order).
__global__ __launch_bounds__(256, 4) void k_level(
        const float* __restrict__ zf, const float* __restrict__ wf,
        const float* __restrict__ accS,
        const float* __restrict__ g32, const double* __restrict__ G2,
        const float* __restrict__ b32,
        int* __restrict__ idxws, int* __restrict__ idxL,
        float* __restrict__ klacc, int lvl) {
    __shared__ float bS[512];
    __shared__ float g2S[512];
    __shared__ float gS[256];
    __shared__ float pb[16][16];
    __shared__ float aS[16], mgS[16];
    __shared__ unsigned short cand[16][256];
    __shared__ int ccnt[16];
    __shared__ int bidxS[16];

    const int tid = threadIdx.x;
    const int tok0 = blockIdx.x * 16;

    // stage
    gS[tid] = g32[tid & 255];
    bS[tid] = b32[lvl * 512 + tid]; bS[tid + 256] = b32[lvl * 512 + tid + 256];
    g2S[tid] = (float)G2[tid]; g2S[tid + 256] = (float)G2[tid + 256];
    if (tid < 16) ccnt[tid] = 0;
    __syncthreads();

    // Phase B: a_n = numpy-pairwise fp32 sum of resid^2 (16 threads/token,
    // R12-validated (t,h,s) split — chains bit-identical to R8).
    {
        int t = tid >> 4, s5 = tid & 15, h = s5 >> 3, s = s5 & 7;
        const float* zr = zf + (tok0 + t) * 256;
        int base = h * 128 + s;
        float x0 = __fsub_rn(zr[base], gS[base]);
        float r = __fmul_rn(x0, x0);
        for (int i = 1; i < 16; ++i) {
            float xv = __fsub_rn(zr[base + i * 8], gS[base + i * 8]);
            r = __fadd_rn(r, __fmul_rn(xv, xv));
        }
        pb[t][h * 8 + s] = r;
    }
    __syncthreads();
    if (tid < 16) {
        float r0[8], r1[8];
        #pragma unroll
        for (int j = 0; j < 8; ++j) { r0[j] = pb[tid][j]; r1[j] = pb[tid][8 + j]; }
        float a = __fadd_rn(np_combine8(r0), np_combine8(r1));
        aS[tid] = a;
        unsigned e = (__float_as_uint(a) >> 23) & 0xffu;
        float ulp = __uint_as_float((e - 23u) << 23);
        mgS[tid] = 2.5f * ulp + 1e-4f * sqrtf(a) / (float)(1 << lvl) + 1e-6f;
    }
    __syncthreads();

    // Phase C/C2: thread (t = tid>>4, s = tid&15) owns codes [s*32, s*32+32)
    // of token t. D bit-identical; Dmax/cand-set order-free; KL order change
    // covered by loss slack 10.24.
    const float inv2f = 1.0f / (float)(1 << (lvl + 3));
    {
        int t = tid >> 4, s = tid & 15;
        const f32x4* ar = (const f32x4*)(accS + (size_t)(tok0 + t) * 512 + s * 32);
        f32x4 Dv[8];
        #pragma unroll
        for (int j = 0; j < 8; ++j) Dv[j] = ar[j];
        float aT = aS[t];
        float m = -3.4e38f;
        #pragma unroll
        for (int j = 0; j < 8; ++j) {
            #pragma unroll
            for (int e = 0; e < 4; ++e) {
                int code = s * 32 + j * 4 + e;
                float c2 = __fsub_rn(__fmul_rn(Dv[j][e], inv2f), g2S[code]);
                float D = -__fsub_rn(__fadd_rn(aT, bS[code]), c2);
                Dv[j][e] = D;
                m = fmaxf(m, D);
            }
        }
        #pragma unroll
        for (int msk = 1; msk < 16; msk <<= 1) m = fmaxf(m, __shfl_xor(m, msk));
        float Dm = m, mg = mgS[t];
        float se = 0.f, sd = 0.f;
        #pragma unroll
        for (int j = 0; j < 8; ++j) {
            #pragma unroll
            for (int e = 0; e < 4; ++e) {
                float D = Dv[j][e];
                float d = Dm - D;
                se += __expf(-d);
                sd += d;
                if (D >= Dm - mg) {
                    int pos = atomicAdd(&ccnt[t], 1);
                    if (pos < 256) cand[t][pos] = (unsigned short)(s * 32 + j * 4 + e);
                }
            }
        }
        #pragma unroll
        for (int msk = 1; msk < 16; msk <<= 1) {
            se += __shfl_xor(se, msk);
            sd += __shfl_xor(sd, msk);
        }
        if (s == 0) {
            float kl = __logf(se) + sd * (1.0f / 512.0f) - LOGK;
            int n = tok0 + t;
            float prev = (lvl == 0) ? 0.0f : klacc[n];
            klacc[n] = prev + 0.1f * kl;
        }
    }
    __syncthreads();

    // Phase E: exact numpy-fp32 dist for candidates. float4 loads for w/z
    // (4x fewer load insts), 16-element groups, unroll 2 (small reg window).
    // fmaf order over j=0..255 identical to the scalar loop.
    {
        int t = tid >> 4, s = tid & 15;
        int n = tok0 + t;
        const float4* zr4 = (const float4*)(zf + n * 256);
        int cnt = ccnt[t]; if (cnt > 256) cnt = 256;
        float aT = aS[t];
        float bD = -3.4e38f; int bI = 0x7fffffff;
        for (int ci = s; ci < cnt; ci += 16) {
            int code = cand[t][ci];
            const float4* wr4 = (const float4*)(wf + (lvl * 512 + code) * 256);
            float c = 0.f;
            #pragma unroll 2
            for (int gq = 0; gq < 16; ++gq) {
                float4 w0 = wr4[gq * 4 + 0], w1 = wr4[gq * 4 + 1];
                float4 w2 = wr4[gq * 4 + 2], w3 = wr4[gq * 4 + 3];
                float4 z0 = zr4[gq * 4 + 0], z1 = zr4[gq * 4 + 1];
                float4 z2 = zr4[gq * 4 + 2], z3 = zr4[gq * 4 + 3];
                int b0 = gq * 16;
                c = fmaf(__fsub_rn(z0.x, gS[b0 + 0]), w0.x, c);
                c = fmaf(__fsub_rn(z0.y, gS[b0 + 1]), w0.y, c);
                c = fmaf(__fsub_rn(z0.z, gS[b0 + 2]), w0.z, c);
                c = fmaf(__fsub_rn(z0.w, gS[b0 + 3]), w0.w, c);
                c = fmaf(__fsub_rn(z1.x, gS[b0 + 4]), w1.x, c);
                c = fmaf(__fsub_rn(z1.y, gS[b0 + 5]), w1.y, c);
                c = fmaf(__fsub_rn(z1.z, gS[b0 + 6]), w1.z, c);
                c = fmaf(__fsub_rn(z1.w, gS[b0 + 7]), w1.w, c);
                c = fmaf(__fsub_rn(z2.x, gS[b0 + 8]), w2.x, c);
                c = fmaf(__fsub_rn(z2.y, gS[b0 + 9]), w2.y, c);
                c = fmaf(__fsub_rn(z2.z, gS[b0 + 10]), w2.z, c);
                c = fmaf(__fsub_rn(z2.w, gS[b0 + 11]), w2.w, c);
                c = fmaf(__fsub_rn(z3.x, gS[b0 + 12]), w3.x, c);
                c = fmaf(__fsub_rn(z3.y, gS[b0 + 13]), w3.y, c);
                c = fmaf(__fsub_rn(z3.z, gS[b0 + 14]), w3.z, c);
                c = fmaf(__fsub_rn(z3.w, gS[b0 + 15]), w3.w, c);
            }
            float D = -__fsub_rn(__fadd_rn(aT, bS[code]), __fadd_rn(c, c));
            if (D > bD || (D == bD && code < bI)) { bD = D; bI = code; }
        }
        #pragma unroll
        for (int msk = 1; msk < 16; msk <<= 1) {
            float oD = __shfl_xor(bD, msk);
            int oI = __shfl_xor(bI, msk);
            if (oD > bD || (oD == bD && oI < bI)) { bD = oD; bI = oI; }
        }
        if (s == 0) bidxS[t] = bI;
    }
    __syncthreads();
    if (tid < 16) {
        int gi = bidxS[tid];
        int n = tok0 + tid;
        idxws[n * 8 + lvl] = gi;
        idxL[lvl * 16384 + n] = gi;
    }
}

// g update + fused G2 + hidden work. Blocks [0,32): R11-verbatim chain (8 dims
// each). Blocks [32,288): Phase A for level lvl+1 into ACCS (T=64). Blocks
// [288,...): probs piggyback for level lvl, n < n_safe. Extra roles never
// touch the done counter.
__global__ __launch_bounds__(256) void k_gsum(const float* __restrict__ w,
        const int* __restrict__ idxL, float* __restrict__ g32,
        double* __restrict__ G2, int* __restrict__ done,
        float* __restrict__ outp, float* __restrict__ accS,
        const f16* __restrict__ zh, const f16* __restrict__ zl,
        const f16* __restrict__ wh, const f16* __restrict__ wl,
        int n_safe, int lvl) {
    const int tid = threadIdx.x;
    if (blockIdx.x >= 288) {
        __shared__ int li[64];
        int tok0 = ((int)blockIdx.x - 288) * 64;
        if (tid < 64) {
            int n = tok0 + tid;
            li[tid] = (n < n_safe) ? idxL[lvl * 16384 + n] : 0;
        }
        __syncthreads();
        f32x4* pb4 = (f32x4*)(outp + OUT_PROBS);
        #pragma unroll
        for (int it = 0; it < 32; ++it) {
            int i = it * 256 + tid;           // 0..8191
            int t = i >> 7, kg = i & 127;
            int n = tok0 + t;
            if (n < n_safe) {
                int rel = li[t] - kg * 4;
                f32x4 v;
                v[0] = (rel == 0) ? 1.0f : 0.0f;
                v[1] = (rel == 1) ? 1.0f : 0.0f;
                v[2] = (rel == 2) ? 1.0f : 0.0f;
                v[3] = (rel == 3) ? 1.0f : 0.0f;
                __builtin_nontemporal_store(v, pb4 + ((size_t)n * 1024 + lvl * 128 + kg));
            }
        }
        return;
    }
    if (blockIdx.x >= 32) {
        // Phase A for level lvl+1 (lvl<7 always here), T=64.
        int tok0 = ((int)blockIdx.x - 32) * 64;
        phaseA64(tid, tok0, lvl + 1, accS, zh, zl, wh, wl);
        return;
    }
    __shared__ float wcol[512 * 13];       // [code][dim(8), stride 13]
    __shared__ float vals[2][8][520];      // [buf][dim][token-in-chunk]
    __shared__ int islast;
    __shared__ float gf[256];
    const int d0 = blockIdx.x * 8;
    {   // stage the 512x8 column slice
        const float* wb = w + lvl * 131072 + d0;
        for (int i = tid; i < 4096; i += 256)
            wcol[(i >> 3) * 13 + (i & 7)] = wb[(i >> 3) * 256 + (i & 7)];
    }
    const int* __restrict__ codes = idxL + lvl * 16384;
    const bool producer = (tid < 192);
    const int cl = tid - 248;              // consumer lane 0..7 when >= 0
    if (producer) {
        for (int k = tid; k < 512; k += 192) {
            int c = codes[k] * 13;
            float v0 = wcol[c], v1 = wcol[c + 1], v2 = wcol[c + 2], v3 = wcol[c + 3];
            float v4 = wcol[c + 4], v5 = wcol[c + 5], v6 = wcol[c + 6], v7 = wcol[c + 7];
            vals[0][0][k] = v0; vals[0][1][k] = v1; vals[0][2][k] = v2; vals[0][3][k] = v3;
            vals[0][4][k] = v4; vals[0][5][k] = v5; vals[0][6][k] = v6; vals[0][7][k] = v7;
        }
    }
    __syncthreads();
    float acc = 0.f;
    for (int ch = 0; ch < 32; ++ch) {
        const int cb = ch & 1, nb = cb ^ 1;
        if (producer) {
            if (ch < 31) {
                int base = (ch + 1) << 9;
                for (int k = tid; k < 512; k += 192) {
                    int c = codes[base + k] * 13;
                    float v0 = wcol[c], v1 = wcol[c + 1], v2 = wcol[c + 2], v3 = wcol[c + 3];
                    float v4 = wcol[c + 4], v5 = wcol[c + 5], v6 = wcol[c + 6], v7 = wcol[c + 7];
                    vals[nb][0][k] = v0; vals[nb][1][k] = v1; vals[nb][2][k] = v2; vals[nb][3][k] = v3;
                    vals[nb][4][k] = v4; vals[nb][5][k] = v5; vals[nb][6][k] = v6; vals[nb][7][k] = v7;
                }
            }
        } else if (cl >= 0) {
            const float4* vp = (const float4*)(&vals[cb][cl][0]);  // 128 float4
            float4 A[16], B[16];
            #pragma unroll
            for (int j = 0; j < 16; ++j) A[j] = vp[j];
            #pragma unroll
            for (int s = 0; s < 8; ++s) {
                if ((s & 1) == 0) {
                    if (s < 7) {
                        #pragma unroll
                        for (int j = 0; j < 16; ++j) B[j] = vp[(s + 1) * 16 + j];
                    }
                    #pragma unroll
                    for (int j = 0; j < 16; ++j) {
                        acc = __fadd_rn(acc, A[j].x);
                        acc = __fadd_rn(acc, A[j].y);
                        acc = __fadd_rn(acc, A[j].z);
                        acc = __fadd_rn(acc, A[j].w);
                    }
                } else {
                    if (s < 7) {
                        #pragma unroll
                        for (int j = 0; j < 16; ++j) A[j] = vp[(s + 1) * 16 + j];
                    }
                    #pragma unroll
                    for (int j = 0; j < 16; ++j) {
                        acc = __fadd_rn(acc, B[j].x);
                        acc = __fadd_rn(acc, B[j].y);
                        acc = __fadd_rn(acc, B[j].z);
                        acc = __fadd_rn(acc, B[j].w);
                    }
                }
            }
        }
        __syncthreads();
    }
    if (cl >= 0) g32[d0 + cl] = __fadd_rn(g32[d0 + cl], acc);
    __threadfence();           // release: own stores visible at device scope
    __syncthreads();
    if (tid == 0) {
        int prev = atomicAdd(done, 1);
        islast = (prev == 31) ? 1 : 0;
    }
    __syncthreads();
    if (islast) {
        if (tid == 0) *done = 0;           // reset for next level
        __threadfence();                   // acquire side
        gf[tid] = atomicAdd(&g32[tid], 0.0f);
        __syncthreads();
        const float* wn = w + (lvl + 1) * 131072;
        for (int k = tid; k < 512; k += 256) {
            const float* wr = wn + k * 256;
            double s = 0.0;
            for (int j = 0; j < 256; ++j) s = fma((double)gf[j], (double)wr[j], s);
            G2[k] = 2.0 * s;
        }
    }
}

// Epilogue 1: q_out (transposed), indices (as float), per-image loss.
// q_out gather uses float4 w loads (sum order over l per d unchanged).
__global__ __launch_bounds__(256) void k_out1(const float* __restrict__ w,
        const float* __restrict__ b32, const int* __restrict__ idxws,
        const float* __restrict__ klacc, float* __restrict__ out) {
    __shared__ int lidx[64][8];
    int tid = threadIdx.x;
    int tok0 = blockIdx.x * 64;
    int b = tok0 >> 10, hw0 = tok0 & 1023;

    for (int s = tid; s < 512; s += 256) {
        int v = idxws[tok0 * 8 + s];
        lidx[s >> 3][s & 7] = v;
        out[OUT_IDX + tok0 * 8 + s] = (float)v;
    }
    __syncthreads();

    {
        int j = tid & 63, q = tid >> 6;
        int id[8];
        #pragma unroll
        for (int l = 0; l < 8; ++l) id[l] = lidx[j][l];
        for (int dd = 0; dd < 64; dd += 4) {
            int d = q * 64 + dd;
            float s0 = 0.f, s1 = 0.f, s2 = 0.f, s3 = 0.f;
            #pragma unroll
            for (int l = 0; l < 8; ++l) {
                float4 wv = *(const float4*)(w + l * 131072 + id[l] * 256 + d);
                s0 += wv.x; s1 += wv.y; s2 += wv.z; s3 += wv.w;
            }
            float* ob = out + b * 262144 + d * 1024 + hw0 + j;
            ob[0] = s0; ob[1024] = s1; ob[2048] = s2; ob[3072] = s3;
        }
    }

    if (tid < 64) {
        int n = tok0 + tid;
        float lv = klacc[n];
        float nl = 0.f;
        #pragma unroll
        for (int jj = 0; jj < 7; ++jj) {
            float up = sqrtf(b32[jj * 512 + lidx[tid][jj]]);
            float lo = sqrtf(b32[(jj + 1) * 512 + lidx[tid][jj + 1]]);
            float ratio = 4.0f * (lo / up);
            float m = fmaxf(ratio, 1.0f) - 1.0f;
            nl += m * m;
        }
        lv += nl * (1.0f / 7.0f) * 0.1f;
        #pragma unroll
        for (int msk = 1; msk < 64; msk <<= 1) lv += __shfl_xor(lv, msk);
        if (tid == 0) atomicAdd(out + OUT_LOSS + b, lv * (1.0f / 1024.0f));
    }
}

// Epilogue 2 (R13 verbatim): blocks [0, nblk_tail) ALL 8 levels for tail
// tokens; blocks >= nblk_tail level-7 only for head tokens. Reads OUT_IDX
// floats (NOT idxws — that's inside the region being overwritten).
__global__ __launch_bounds__(256) void k_out2(float* __restrict__ out,
                                              int tail0, int nblk_tail) {
    int tid = threadIdx.x;
    if ((int)blockIdx.x < nblk_tail) {
        __shared__ int lidx[16][8];
        int tok0 = tail0 + blockIdx.x * 16;
        if (tid < 128) {
            int v = (int)out[OUT_IDX + tok0 * 8 + tid];
            lidx[tid >> 3][tid & 7] = v;
        }
        __syncthreads();
        f32x4* pb = (f32x4*)(out + OUT_PROBS) + (size_t)tok0 * 1024;
        for (int it = 0; it < 64; ++it) {
            int i = it * 256 + tid;
            int nl_ = i >> 10, l = (i >> 7) & 7, kg = i & 127;
            int rel = lidx[nl_][l] - kg * 4;
            f32x4 v;
            v[0] = (rel == 0) ? 1.0f : 0.0f;
            v[1] = (rel == 1) ? 1.0f : 0.0f;
            v[2] = (rel == 2) ? 1.0f : 0.0f;
            v[3] = (rel == 3) ? 1.0f : 0.0f;
            __builtin_nontemporal_store(v, pb + i);
        }
    } else {
        __shared__ int l7[16];
        int tok0 = ((int)blockIdx.x - nblk_tail) * 16;
        if (tok0 >= tail0) return;
        if (tid < 16) l7[tid] = (int)out[OUT_IDX + (tok0 + tid) * 8 + 7];
        __syncthreads();
        f32x4* pb = (f32x4*)(out + OUT_PROBS);
        #pragma unroll
        for (int it = 0; it < 8; ++it) {
            int i = it * 256 + tid;           // 0..2047
            int t = i >> 7, kg = i & 127;
            int rel = l7[t] - kg * 4;
            f32x4 v;
            v[0] = (rel == 0) ? 1.0f : 0.0f;
            v[1] = (rel == 1) ? 1.0f : 0.0f;
            v[2] = (rel == 2) ? 1.0f : 0.0f;
            v[3] = (rel == 3) ? 1.0f : 0.0f;
            __builtin_nontemporal_store(v, pb + (size_t)(tok0 + t) * 1024 + 7 * 128 + kg);
        }
    }
}

extern "C" void kernel_launch(void* const* d_in, const int* in_sizes, int n_in,
                              void* d_out, int out_size, void* d_ws, size_t ws_size,
                              hipStream_t stream) {
    const float* z = (const float*)d_in[0];
    const float* w = (const float*)d_in[1];
    float* out = (float*)d_out;

    float* sb = out + (out_size - SCR_FLOATS);
    f16* zh = (f16*)(sb + SF_ZH);
    f16* zl = (f16*)(sb + SF_ZL);
    f16* wh = (f16*)(sb + SF_WH);
    f16* wl = (f16*)(sb + SF_WL);
    float* b32 = (float*)(sb + SF_B32);
    float* g32 = (float*)(sb + SF_G32);
    double* G2 = (double*)(sb + SF_G2D);
    int* idxws = (int*)(sb + SF_IDX);
    int* idxL = (int*)(sb + SF_IDXL);
    float* klacc = (float*)(sb + SF_KL);
    int* done = (int*)(sb + SF_DONE);
    float* accS = (float*)(sb + SF_ACC);

    // Tokens whose probs slices lie entirely below the scratch tail get their
    // probs written during the level loop. out_size=71,434,256 ->
    // n_safe=12986, tail0=12976, 213 tail blocks + 811 head(level-7) blocks.
    long scr_off = (long)out_size - SCR_FLOATS - OUT_PROBS;   // floats into probs
    int n_safe = (int)(scr_off >> 12);
    if (n_safe > 16384) n_safe = 16384;
    if (n_safe < 0) n_safe = 0;
    int tail0 = n_safe & ~15;
    int nblk_tail = (16384 - tail0) / 16;
    int nblk_head = tail0 / 16;
    int pgrid = (n_safe + 63) / 64;        // probs piggyback blocks per gsum

    k_prep<<<5392, 256, 0, stream>>>(z, w, zh, zl, wh, wl, b32, g32, G2,
                                     out + OUT_LOSS, done, accS);
    for (int l = 0; l < 8; ++l) {
        k_level<<<1024, 256, 0, stream>>>(z, w, accS, g32, G2, b32,
                                          idxws, idxL, klacc, l);
        if (l < 7)
            k_gsum<<<288 + pgrid, 256, 0, stream>>>(w, idxL, g32, G2, done,
                                                    out, accS, zh, zl, wh, wl,
                                                    n_safe, l);
    }
    k_out1<<<256, 256, 0, stream>>>(w, b32, idxws, klacc, out);
    k_out2<<<nblk_tail + nblk_head, 256, 0, stream>>>(out, tail0, nblk_tail);
}

// Round 12
// 1223.305 us; speedup vs baseline: 1.0002x; 1.0002x over previous
//
#include <hip/hip_runtime.h>

// HierarchicalResidualQuantizer on gfx950 — numpy-fp32-exact decision path.
// N=16384 tokens, D=256, L=8 levels, K=512 codes.
// Outputs (flat fp32 in d_out): q_out[16,256,32,32] @0, indices[16,32,32,8] @4194304,
// loss[16] @4325376, all_probs[16384,8,512] @4325392.  Total 71,434,256 floats.
// Scratch lives in the TAIL of the probs region.
//
// R19 (on R18's 1223us; R18 proved Phase E is NOT the k_level cost):
// (1) TILED fragment layout for zh/zl, wh/wl: [group16][k0idx][lane64][8] so
//     Phase-A fragment loads are ONE coalesced 1KB wave-transaction instead of
//     16 scattered 16B row-pieces (Phase-A MFMA work is ~7-14us but measured
//     ~4-5x that -> load-bound, the classic uncoalesced-fragment pattern).
//     Values element-identical, MFMA order identical -> ACCS bit-identical.
// (2) k_out2's head-token level-7 probs role merged into k_out1's grid (head
//     probs touch only the scratch-free region; no conflict with out1 reads).
//     k_out2 is tail-only.
// Carried: Phase-A hoist via ACCS (T=64 in gsum/prep), T=16 k_level grid 1024,
// gsum probs piggyback, merged prep, R13 epilogue ordering.

typedef _Float16 f16;
typedef _Float16 half8 __attribute__((ext_vector_type(8)));
typedef _Float16 half4v __attribute__((ext_vector_type(4)));
typedef float f32x4 __attribute__((ext_vector_type(4)));

#define LOGK 6.238324625039508f

#define OUT_IDX 4194304
#define OUT_LOSS 4325376
#define OUT_PROBS 4325392

#define SCR_FLOATS 13915408
// scratch offsets in floats
#define SF_ZH 0              // f16[16384*256] TILED z hi
#define SF_ZL 2097152        // f16[16384*256] TILED z lo
#define SF_WH 4194304        // f16[4096*256]  TILED w hi
#define SF_WL 4718592        // f16[4096*256]  TILED w lo
#define SF_B32 5242880       // float[4096]  fp32 pairwise ||w||^2 (numpy-exact)
#define SF_G32 5246976       // float[256]   fp32 global_sum (numpy-exact bits)
#define SF_G2D 5247232       // double[512]  2*g.w_k for next level
#define SF_IDX 5248256       // int[16384*8]
#define SF_IDXL 5379328      // int[8*16384] level-major indices
#define SF_KL 5510400        // float[16384]
#define SF_DONE 5526784      // int[1] cross-block counter (+pad)
#define SF_ACC 5526800       // float[16384*512] Phase-A scores for current level

// Tiled index: element (row16-group g16, lane-row lr, col d) with
// kx=d>>5, quad=(d>>3)&3, j=d&7 lives at ((g16*8+kx)*64 + quad*16+lr)*8 + j.
// A wave's fragment load (lane = quad*16+lr reads its 8 elems) is then 64
// consecutive 16B chunks -> fully coalesced.

// ---------- numpy pairwise-128 block: 8 accumulators + fixed combine tree ----------
__device__ __forceinline__ float np_combine8(const float r[8]) {
    return __fadd_rn(__fadd_rn(__fadd_rn(r[0], r[1]), __fadd_rn(r[2], r[3])),
                     __fadd_rn(__fadd_rn(r[4], r[5]), __fadd_rn(r[6], r[7])));
}

// hi/lo fp16 split of 8 scaled floats — identical arithmetic to prep's split.
__device__ __forceinline__ void cvt8(const float* p, float sc, half8& h, half8& l) {
    #pragma unroll
    for (int j = 0; j < 8; ++j) {
        float v = p[j] * sc;
        f16 hh = (f16)v;
        h[j] = hh;
        l[j] = (f16)(v - (float)hh);
    }
}

// Phase A, T=64 tokens / 256 threads (4 waves), two code-passes of 256 codes,
// TILED fragment loads. MFMA order per (token,code): per k0 ascending,
// (hi*bh, hi*bl, lo*bh) — R8-exact; fragments element-identical to the
// row-major path -> ACCS bit-identical.
__device__ __forceinline__ void phaseA64(
        int tid, int tok0, int lvl, float* __restrict__ accS,
        const f16* __restrict__ zt_h, const f16* __restrict__ zt_l,
        const f16* __restrict__ wt_h, const f16* __restrict__ wt_l) {
    const int wave = tid >> 6, lane = tid & 63;
    const int quad = lane >> 4, lr = lane & 15;
    const int g16b = tok0 >> 4;
    #pragma unroll
    for (int cp = 0; cp < 2; ++cp) {
        const int code0 = cp * 256 + wave * 64;
        const int c16b = lvl * 32 + (code0 >> 4);
        f32x4 acc[4][4];
        #pragma unroll
        for (int g = 0; g < 4; ++g)
            #pragma unroll
            for (int nt = 0; nt < 4; ++nt)
                acc[g][nt] = (f32x4){0.f, 0.f, 0.f, 0.f};
        for (int kx = 0; kx < 8; ++kx) {
            half8 ah[4], al[4];
            #pragma unroll
            for (int g = 0; g < 4; ++g) {
                int off = (((g16b + g) * 8 + kx) * 64 + lane) * 8;
                ah[g] = *(const half8*)(zt_h + off);
                al[g] = *(const half8*)(zt_l + off);
            }
            half8 bh[4], bl[4];
            #pragma unroll
            for (int nt = 0; nt < 4; ++nt) {
                int off = (((c16b + nt) * 8 + kx) * 64 + lane) * 8;
                bh[nt] = *(const half8*)(wt_h + off);
                bl[nt] = *(const half8*)(wt_l + off);
            }
            #pragma unroll
            for (int nt = 0; nt < 4; ++nt)
                #pragma unroll
                for (int g = 0; g < 4; ++g) {
                    acc[g][nt] = __builtin_amdgcn_mfma_f32_16x16x32_f16(ah[g], bh[nt], acc[g][nt], 0, 0, 0);
                    acc[g][nt] = __builtin_amdgcn_mfma_f32_16x16x32_f16(ah[g], bl[nt], acc[g][nt], 0, 0, 0);
                    acc[g][nt] = __builtin_amdgcn_mfma_f32_16x16x32_f16(al[g], bh[nt], acc[g][nt], 0, 0, 0);
                }
        }
        #pragma unroll
        for (int g = 0; g < 4; ++g)
            #pragma unroll
            for (int r = 0; r < 4; ++r) {
                int token = tok0 + g * 16 + quad * 4 + r;
                float* dst = accS + (size_t)token * 512 + code0 + lr;
                #pragma unroll
                for (int nt = 0; nt < 4; ++nt)
                    dst[nt * 16] = acc[g][nt][r];
            }
    }
}

// fp32-direct Phase A T=64 (level 0, inside prep): reads RAW z,w (identical
// split arithmetic, no dependency on the split blocks).  (R17 verbatim.)
__device__ __forceinline__ void phaseA64_f32(
        int tid, int tok0, float* __restrict__ accS,
        const float* __restrict__ z, const float* __restrict__ w) {
    const int wave = tid >> 6, lane = tid & 63;
    const int quad = lane >> 4, lr = lane & 15;
    const float sc = 16.0f;                                    // 1<<(0+4)
    #pragma unroll
    for (int cp = 0; cp < 2; ++cp) {
        const int code0 = cp * 256 + wave * 64;
        const float* zr = z + (tok0 + lr) * 256 + quad * 8;
        const float* wr = w + (code0 + lr) * 256 + quad * 8;   // lvl 0
        f32x4 acc[4][4];
        #pragma unroll
        for (int g = 0; g < 4; ++g)
            #pragma unroll
            for (int nt = 0; nt < 4; ++nt)
                acc[g][nt] = (f32x4){0.f, 0.f, 0.f, 0.f};
        for (int k0 = 0; k0 < 256; k0 += 32) {
            half8 ah[4], al[4];
            #pragma unroll
            for (int g = 0; g < 4; ++g)
                cvt8(zr + g * 16 * 256 + k0, 1.0f, ah[g], al[g]);
            half8 bh[4], bl[4];
            #pragma unroll
            for (int nt = 0; nt < 4; ++nt)
                cvt8(wr + nt * 16 * 256 + k0, sc, bh[nt], bl[nt]);
            #pragma unroll
            for (int nt = 0; nt < 4; ++nt)
                #pragma unroll
                for (int g = 0; g < 4; ++g) {
                    acc[g][nt] = __builtin_amdgcn_mfma_f32_16x16x32_f16(ah[g], bh[nt], acc[g][nt], 0, 0, 0);
                    acc[g][nt] = __builtin_amdgcn_mfma_f32_16x16x32_f16(ah[g], bl[nt], acc[g][nt], 0, 0, 0);
                    acc[g][nt] = __builtin_amdgcn_mfma_f32_16x16x32_f16(al[g], bh[nt], acc[g][nt], 0, 0, 0);
                }
        }
        #pragma unroll
        for (int g = 0; g < 4; ++g)
            #pragma unroll
            for (int r = 0; r < 4; ++r) {
                int token = tok0 + g * 16 + quad * 4 + r;
                float* dst = accS + (size_t)token * 512 + code0 + lr;
                #pragma unroll
                for (int nt = 0; nt < 4; ++nt)
                    dst[nt * 16] = acc[g][nt][r];
            }
    }
}

// Fused prep: [0,4096) z hi/lo split -> TILED layout, [4096,5120) w hi/lo
// split -> TILED layout, [5120,5136) ||w||^2 + misc init, [5136,5392)
// Phase A level 0 (fp32-direct, T=64).
__global__ __launch_bounds__(256) void k_prep(
        const float* __restrict__ z, const float* __restrict__ w,
        f16* __restrict__ zh, f16* __restrict__ zl,
        f16* __restrict__ wh, f16* __restrict__ wl,
        float* __restrict__ b32, float* __restrict__ g32,
        double* __restrict__ G2, float* __restrict__ loss_out,
        int* __restrict__ done, float* __restrict__ accS) {
    const int bid = blockIdx.x;
    const int tid = threadIdx.x;
    if (bid < 4096) {
        int i = (bid * 256 + tid) * 4;
        int n = i >> 8, d = i & 255;
        float4 v = *(const float4*)(z + i);
        half4v h, l;
        float c0 = v.x, c1 = v.y, c2 = v.z, c3 = v.w;
        f16 h0 = (f16)c0, h1 = (f16)c1, h2 = (f16)c2, h3 = (f16)c3;
        h[0] = h0; h[1] = h1; h[2] = h2; h[3] = h3;
        l[0] = (f16)(c0 - (float)h0); l[1] = (f16)(c1 - (float)h1);
        l[2] = (f16)(c2 - (float)h2); l[3] = (f16)(c3 - (float)h3);
        int g16 = n >> 4, lr = n & 15;
        int kx = d >> 5, quad = (d >> 3) & 3, j = d & 7;   // j in {0,4}
        int dst = ((g16 * 8 + kx) * 64 + quad * 16 + lr) * 8 + j;
        *(half4v*)(zh + dst) = h;
        *(half4v*)(zl + dst) = l;
    } else if (bid < 5120) {
        int row = (bid - 4096) * 4 + (tid >> 6);
        int lane = tid & 63;
        int lvl = row >> 9;
        int code_in = row & 511;
        float sc = (float)(1 << (lvl + 4));
        const float* wr = w + row * 256;
        int d0 = lane * 4;
        float4 v = *(const float4*)(wr + d0);
        half4v h, l;
        float s0 = v.x * sc, s1 = v.y * sc, s2 = v.z * sc, s3 = v.w * sc;
        f16 h0 = (f16)s0, h1 = (f16)s1, h2 = (f16)s2, h3 = (f16)s3;
        h[0] = h0; h[1] = h1; h[2] = h2; h[3] = h3;
        l[0] = (f16)(s0 - (float)h0); l[1] = (f16)(s1 - (float)h1);
        l[2] = (f16)(s2 - (float)h2); l[3] = (f16)(s3 - (float)h3);
        int c16 = code_in >> 4, lr = code_in & 15;
        int kx = d0 >> 5, quad = (d0 >> 3) & 3, j = d0 & 7;
        int dst = (((lvl * 32 + c16) * 8 + kx) * 64 + quad * 16 + lr) * 8 + j;
        *(half4v*)(wh + dst) = h;
        *(half4v*)(wl + dst) = l;
    } else if (bid < 5136) {
        int b = bid - 5120;                 // 0..15
        int row = b * 256 + tid;            // 0..4095
        const float* wr = w + row * 256;
        float res[2];
        #pragma unroll
        for (int h = 0; h < 2; ++h) {
            const float* x = wr + h * 128;
            float r[8];
            #pragma unroll
            for (int j = 0; j < 8; ++j) r[j] = __fmul_rn(x[j], x[j]);
            for (int i = 8; i < 128; i += 8)
                #pragma unroll
                for (int j = 0; j < 8; ++j) r[j] = __fadd_rn(r[j], __fmul_rn(x[i + j], x[i + j]));
            res[h] = np_combine8(r);
        }
        b32[row] = __fadd_rn(res[0], res[1]);
        if (b == 0) {
            g32[tid] = 0.0f;
            G2[tid] = 0.0; G2[tid + 256] = 0.0;
            if (tid < 16) loss_out[tid] = 0.0f;
            if (tid == 0) *done = 0;
        }
    } else {
        int tok0 = (bid - 5136) * 64;
        phaseA64_f32(tid, tok0, accS, z, w);
    }
}

// Per-level, 16 tokens/block, 256 threads, grid 1024 (4 blocks/CU).
// Phase A is PRE-COMPUTED in ACCS. B (R12-validated 16-thread split) ->
// C/C2 (thread owns 32 codes of its token) -> KL -> E (float4, exact order).
__global__ __launch_bounds__(256, 4) void k_level(
        const float* __restrict__ zf, const float* __restrict__ wf,
        const float* __restrict__ accS,
        const float* __restrict__ g32, const double* __restrict__ G2,
        const float* __restrict__ b32,
        int* __restrict__ idxws, int* __restrict__ idxL,
        float* __restrict__ klacc, int lvl) {
    __shared__ float bS[512];
    __shared__ float g2S[512];
    __shared__ float gS[256];
    __shared__ float pb[16][16];
    __shared__ float aS[16], mgS[16];
    __shared__ unsigned short cand[16][256];
    __shared__ int ccnt[16];
    __shared__ int bidxS[16];

    const int tid = threadIdx.x;
    const int tok0 = blockIdx.x * 16;

    // stage
    gS[tid] = g32[tid & 255];
    bS[tid] = b32[lvl * 512 + tid]; bS[tid + 256] = b32[lvl * 512 + tid + 256];
    g2S[tid] = (float)G2[tid]; g2S[tid + 256] = (float)G2[tid + 256];
    if (tid < 16) ccnt[tid] = 0;
    __syncthreads();

    // Phase B: a_n = numpy-pairwise fp32 sum of resid^2 (16 threads/token,
    // R12-validated (t,h,s) split — chains bit-identical to R8).
    {
        int t = tid >> 4, s5 = tid & 15, h = s5 >> 3, s = s5 & 7;
        const float* zr = zf + (tok0 + t) * 256;
        int base = h * 128 + s;
        float x0 = __fsub_rn(zr[base], gS[base]);
        float r = __fmul_rn(x0, x0);
        for (int i = 1; i < 16; ++i) {
            float xv = __fsub_rn(zr[base + i * 8], gS[base + i * 8]);
            r = __fadd_rn(r, __fmul_rn(xv, xv));
        }
        pb[t][h * 8 + s] = r;
    }
    __syncthreads();
    if (tid < 16) {
        float r0[8], r1[8];
        #pragma unroll
        for (int j = 0; j < 8; ++j) { r0[j] = pb[tid][j]; r1[j] = pb[tid][8 + j]; }
        float a = __fadd_rn(np_combine8(r0), np_combine8(r1));
        aS[tid] = a;
        unsigned e = (__float_as_uint(a) >> 23) & 0xffu;
        float ulp = __uint_as_float((e - 23u) << 23);
        mgS[tid] = 2.5f * ulp + 1e-4f * sqrtf(a) / (float)(1 << lvl) + 1e-6f;
    }
    __syncthreads();

    // Phase C/C2: thread (t = tid>>4, s = tid&15) owns codes [s*32, s*32+32)
    // of token t. D bit-identical; Dmax/cand-set order-free; KL order change
    // covered by loss slack 10.24.
    const float inv2f = 1.0f / (float)(1 << (lvl + 3));
    {
        int t = tid >> 4, s = tid & 15;
        const f32x4* ar = (const f32x4*)(accS + (size_t)(tok0 + t) * 512 + s * 32);
        f32x4 Dv[8];
        #pragma unroll
        for (int j = 0; j < 8; ++j) Dv[j] = ar[j];
        float aT = aS[t];
        float m = -3.4e38f;
        #pragma unroll
        for (int j = 0; j < 8; ++j) {
            #pragma unroll
            for (int e = 0; e < 4; ++e) {
                int code = s * 32 + j * 4 + e;
                float c2 = __fsub_rn(__fmul_rn(Dv[j][e], inv2f), g2S[code]);
                float D = -__fsub_rn(__fadd_rn(aT, bS[code]), c2);
                Dv[j][e] = D;
                m = fmaxf(m, D);
            }
        }
        #pragma unroll
        for (int msk = 1; msk < 16; msk <<= 1) m = fmaxf(m, __shfl_xor(m, msk));
        float Dm = m, mg = mgS[t];
        float se = 0.f, sd = 0.f;
        #pragma unroll
        for (int j = 0; j < 8; ++j) {
            #pragma unroll
            for (int e = 0; e < 4; ++e) {
                float D = Dv[j][e];
                float d = Dm - D;
                se += __expf(-d);
                sd += d;
                if (D >= Dm - mg) {
                    int pos = atomicAdd(&ccnt[t], 1);
                    if (pos < 256) cand[t][pos] = (unsigned short)(s * 32 + j * 4 + e);
                }
            }
        }
        #pragma unroll
        for (int msk = 1; msk < 16; msk <<= 1) {
            se += __shfl_xor(se, msk);
            sd += __shfl_xor(sd, msk);
        }
        if (s == 0) {
            float kl = __logf(se) + sd * (1.0f / 512.0f) - LOGK;
            int n = tok0 + t;
            float prev = (lvl == 0) ? 0.0f : klacc[n];
            klacc[n] = prev + 0.1f * kl;
        }
    }
    __syncthreads();

    // Phase E: exact numpy-fp32 dist for candidates. float4 loads, 16-elem
    // groups, unroll 2. fmaf order over j=0..255 identical to scalar loop.
    {
        int t = tid >> 4, s = tid & 15;
        int n = tok0 + t;
        const float4* zr4 = (const float4*)(zf + n * 256);
        int cnt = ccnt[t]; if (cnt > 256) cnt = 256;
        float aT = aS[t];
        float bD = -3.4e38f; int bI = 0x7fffffff;
        for (int ci = s; ci < cnt; ci += 16) {
            int code = cand[t][ci];
            const float4* wr4 = (const float4*)(wf + (lvl * 512 + code) * 256);
            float c = 0.f;
            #pragma unroll 2
            for (int gq = 0; gq < 16; ++gq) {
                float4 w0 = wr4[gq * 4 + 0], w1 = wr4[gq * 4 + 1];
                float4 w2 = wr4[gq * 4 + 2], w3 = wr4[gq * 4 + 3];
                float4 z0 = zr4[gq * 4 + 0], z1 = zr4[gq * 4 + 1];
                float4 z2 = zr4[gq * 4 + 2], z3 = zr4[gq * 4 + 3];
                int b0 = gq * 16;
                c = fmaf(__fsub_rn(z0.x, gS[b0 + 0]), w0.x, c);
                c = fmaf(__fsub_rn(z0.y, gS[b0 + 1]), w0.y, c);
                c = fmaf(__fsub_rn(z0.z, gS[b0 + 2]), w0.z, c);
                c = fmaf(__fsub_rn(z0.w, gS[b0 + 3]), w0.w, c);
                c = fmaf(__fsub_rn(z1.x, gS[b0 + 4]), w1.x, c);
                c = fmaf(__fsub_rn(z1.y, gS[b0 + 5]), w1.y, c);
                c = fmaf(__fsub_rn(z1.z, gS[b0 + 6]), w1.z, c);
                c = fmaf(__fsub_rn(z1.w, gS[b0 + 7]), w1.w, c);
                c = fmaf(__fsub_rn(z2.x, gS[b0 + 8]), w2.x, c);
                c = fmaf(__fsub_rn(z2.y, gS[b0 + 9]), w2.y, c);
                c = fmaf(__fsub_rn(z2.z, gS[b0 + 10]), w2.z, c);
                c = fmaf(__fsub_rn(z2.w, gS[b0 + 11]), w2.w, c);
                c = fmaf(__fsub_rn(z3.x, gS[b0 + 12]), w3.x, c);
                c = fmaf(__fsub_rn(z3.y, gS[b0 + 13]), w3.y, c);
                c = fmaf(__fsub_rn(z3.z, gS[b0 + 14]), w3.z, c);
                c = fmaf(__fsub_rn(z3.w, gS[b0 + 15]), w3.w, c);
            }
            float D = -__fsub_rn(__fadd_rn(aT, bS[code]), __fadd_rn(c, c));
            if (D > bD || (D == bD && code < bI)) { bD = D; bI = code; }
        }
        #pragma unroll
        for (int msk = 1; msk < 16; msk <<= 1) {
            float oD = __shfl_xor(bD, msk);
            int oI = __shfl_xor(bI, msk);
            if (oD > bD || (oD == bD && oI < bI)) { bD = oD; bI = oI; }
        }
        if (s == 0) bidxS[t] = bI;
    }
    __syncthreads();
    if (tid < 16) {
        int gi = bidxS[tid];
        int n = tok0 + tid;
        idxws[n * 8 + lvl] = gi;
        idxL[lvl * 16384 + n] = gi;
    }
}

// g update + fused G2 + hidden work. Blocks [0,32): R11-verbatim chain (8 dims
// each). Blocks [32,288): Phase A for level lvl+1 into ACCS (T=64, tiled
// loads). Blocks [288,...): probs piggyback for level lvl, n < n_safe. Extra
// roles never touch the done counter.
__global__ __launch_bounds__(256) void k_gsum(const float* __restrict__ w,
        const int* __restrict__ idxL, float* __restrict__ g32,
        double* __restrict__ G2, int* __restrict__ done,
        float* __restrict__ outp, float* __restrict__ accS,
        const f16* __restrict__ zh, const f16* __restrict__ zl,
        const f16* __restrict__ wh, const f16* __restrict__ wl,
        int n_safe, int lvl) {
    const int tid = threadIdx.x;
    if (blockIdx.x >= 288) {
        __shared__ int li[64];
        int tok0 = ((int)blockIdx.x - 288) * 64;
        if (tid < 64) {
            int n = tok0 + tid;
            li[tid] = (n < n_safe) ? idxL[lvl * 16384 + n] : 0;
        }
        __syncthreads();
        f32x4* pb4 = (f32x4*)(outp + OUT_PROBS);
        #pragma unroll
        for (int it = 0; it < 32; ++it) {
            int i = it * 256 + tid;           // 0..8191
            int t = i >> 7, kg = i & 127;
            int n = tok0 + t;
            if (n < n_safe) {
                int rel = li[t] - kg * 4;
                f32x4 v;
                v[0] = (rel == 0) ? 1.0f : 0.0f;
                v[1] = (rel == 1) ? 1.0f : 0.0f;
                v[2] = (rel == 2) ? 1.0f : 0.0f;
                v[3] = (rel == 3) ? 1.0f : 0.0f;
                __builtin_nontemporal_store(v, pb4 + ((size_t)n * 1024 + lvl * 128 + kg));
            }
        }
        return;
    }
    if (blockIdx.x >= 32) {
        // Phase A for level lvl+1 (lvl<7 always here), T=64, tiled loads.
        int tok0 = ((int)blockIdx.x - 32) * 64;
        phaseA64(tid, tok0, lvl + 1, accS, zh, zl, wh, wl);
        return;
    }
    __shared__ float wcol[512 * 13];       // [code][dim(8), stride 13]
    __shared__ float vals[2][8][520];      // [buf][dim][token-in-chunk]
    __shared__ int islast;
    __shared__ float gf[256];
    const int d0 = blockIdx.x * 8;
    {   // stage the 512x8 column slice
        const float* wb = w + lvl * 131072 + d0;
        for (int i = tid; i < 4096; i += 256)
            wcol[(i >> 3) * 13 + (i & 7)] = wb[(i >> 3) * 256 + (i & 7)];
    }
    const int* __restrict__ codes = idxL + lvl * 16384;
    const bool producer = (tid < 192);
    const int cl = tid - 248;              // consumer lane 0..7 when >= 0
    if (producer) {
        for (int k = tid; k < 512; k += 192) {
            int c = codes[k] * 13;
            float v0 = wcol[c], v1 = wcol[c + 1], v2 = wcol[c + 2], v3 = wcol[c + 3];
            float v4 = wcol[c + 4], v5 = wcol[c + 5], v6 = wcol[c + 6], v7 = wcol[c + 7];
            vals[0][0][k] = v0; vals[0][1][k] = v1; vals[0][2][k] = v2; vals[0][3][k] = v3;
            vals[0][4][k] = v4; vals[0][5][k] = v5; vals[0][6][k] = v6; vals[0][7][k] = v7;
        }
    }
    __syncthreads();
    float acc = 0.f;
    for (int ch = 0; ch < 32; ++ch) {
        const int cb = ch & 1, nb = cb ^ 1;
        if (producer) {
            if (ch < 31) {
                int base = (ch + 1) << 9;
                for (int k = tid; k < 512; k += 192) {
                    int c = codes[base + k] * 13;
                    float v0 = wcol[c], v1 = wcol[c + 1], v2 = wcol[c + 2], v3 = wcol[c + 3];
                    float v4 = wcol[c + 4], v5 = wcol[c + 5], v6 = wcol[c + 6], v7 = wcol[c + 7];
                    vals[nb][0][k] = v0; vals[nb][1][k] = v1; vals[nb][2][k] = v2; vals[nb][3][k] = v3;
                    vals[nb][4][k] = v4; vals[nb][5][k] = v5; vals[nb][6][k] = v6; vals[nb][7][k] = v7;
                }
            }
        } else if (cl >= 0) {
            const float4* vp = (const float4*)(&vals[cb][cl][0]);  // 128 float4
            float4 A[16], B[16];
            #pragma unroll
            for (int j = 0; j < 16; ++j) A[j] = vp[j];
            #pragma unroll
            for (int s = 0; s < 8; ++s) {
                if ((s & 1) == 0) {
                    if (s < 7) {
                        #pragma unroll
                        for (int j = 0; j < 16; ++j) B[j] = vp[(s + 1) * 16 + j];
                    }
                    #pragma unroll
                    for (int j = 0; j < 16; ++j) {
                        acc = __fadd_rn(acc, A[j].x);
                        acc = __fadd_rn(acc, A[j].y);
                        acc = __fadd_rn(acc, A[j].z);
                        acc = __fadd_rn(acc, A[j].w);
                    }
                } else {
                    if (s < 7) {
                        #pragma unroll
                        for (int j = 0; j < 16; ++j) A[j] = vp[(s + 1) * 16 + j];
                    }
                    #pragma unroll
                    for (int j = 0; j < 16; ++j) {
                        acc = __fadd_rn(acc, B[j].x);
                        acc = __fadd_rn(acc, B[j].y);
                        acc = __fadd_rn(acc, B[j].z);
                        acc = __fadd_rn(acc, B[j].w);
                    }
                }
            }
        }
        __syncthreads();
    }
    if (cl >= 0) g32[d0 + cl] = __fadd_rn(g32[d0 + cl], acc);
    __threadfence();           // release: own stores visible at device scope
    __syncthreads();
    if (tid == 0) {
        int prev = atomicAdd(done, 1);
        islast = (prev == 31) ? 1 : 0;
    }
    __syncthreads();
    if (islast) {
        if (tid == 0) *done = 0;           // reset for next level
        __threadfence();                   // acquire side
        gf[tid] = atomicAdd(&g32[tid], 0.0f);
        __syncthreads();
        const float* wn = w + (lvl + 1) * 131072;
        for (int k = tid; k < 512; k += 256) {
            const float* wr = wn + k * 256;
            double s = 0.0;
            for (int j = 0; j < 256; ++j) s = fma((double)gf[j], (double)wr[j], s);
            G2[k] = 2.0 * s;
        }
    }
}

// Merged epilogue 1. Blocks [0,256): q_out (float4 gather) + indices + loss.
// Blocks [256, 256+nblk_head): level-7 one-hot probs for HEAD tokens (safe
// region only — does not touch scratch, so no conflict with the out1 role's
// klacc/idxws reads).
__global__ __launch_bounds__(256) void k_out1(const float* __restrict__ w,
        const float* __restrict__ b32, const int* __restrict__ idxws,
        const float* __restrict__ klacc, float* __restrict__ out, int tail0) {
    int tid = threadIdx.x;
    if (blockIdx.x >= 256) {
        __shared__ int l7[16];
        int tok0 = ((int)blockIdx.x - 256) * 16;
        if (tok0 >= tail0) return;
        if (tid < 16) l7[tid] = idxws[(tok0 + tid) * 8 + 7];
        __syncthreads();
        f32x4* pb = (f32x4*)(out + OUT_PROBS);
        #pragma unroll
        for (int it = 0; it < 8; ++it) {
            int i = it * 256 + tid;           // 0..2047
            int t = i >> 7, kg = i & 127;
            int rel = l7[t] - kg * 4;
            f32x4 v;
            v[0] = (rel == 0) ? 1.0f : 0.0f;
            v[1] = (rel == 1) ? 1.0f : 0.0f;
            v[2] = (rel == 2) ? 1.0f : 0.0f;
            v[3] = (rel == 3) ? 1.0f : 0.0f;
            __builtin_nontemporal_store(v, pb + (size_t)(tok0 + t) * 1024 + 7 * 128 + kg);
        }
        return;
    }
    __shared__ int lidx[64][8];
    int tok0 = blockIdx.x * 64;
    int b = tok0 >> 10, hw0 = tok0 & 1023;

    for (int s = tid; s < 512; s += 256) {
        int v = idxws[tok0 * 8 + s];
        lidx[s >> 3][s & 7] = v;
        out[OUT_IDX + tok0 * 8 + s] = (float)v;
    }
    __syncthreads();

    {
        int j = tid & 63, q = tid >> 6;
        int id[8];
        #pragma unroll
        for (int l = 0; l < 8; ++l) id[l] = lidx[j][l];
        for (int dd = 0; dd < 64; dd += 4) {
            int d = q * 64 + dd;
            float s0 = 0.f, s1 = 0.f, s2 = 0.f, s3 = 0.f;
            #pragma unroll
            for (int l = 0; l < 8; ++l) {
                float4 wv = *(const float4*)(w + l * 131072 + id[l] * 256 + d);
                s0 += wv.x; s1 += wv.y; s2 += wv.z; s3 += wv.w;
            }
            float* ob = out + b * 262144 + d * 1024 + hw0 + j;
            ob[0] = s0; ob[1024] = s1; ob[2048] = s2; ob[3072] = s3;
        }
    }

    if (tid < 64) {
        int n = tok0 + tid;
        float lv = klacc[n];
        float nl = 0.f;
        #pragma unroll
        for (int jj = 0; jj < 7; ++jj) {
            float up = sqrtf(b32[jj * 512 + lidx[tid][jj]]);
            float lo = sqrtf(b32[(jj + 1) * 512 + lidx[tid][jj + 1]]);
            float ratio = 4.0f * (lo / up);
            float m = fmaxf(ratio, 1.0f) - 1.0f;
            nl += m * m;
        }
        lv += nl * (1.0f / 7.0f) * 0.1f;
        #pragma unroll
        for (int msk = 1; msk < 64; msk <<= 1) lv += __shfl_xor(lv, msk);
        if (tid == 0) atomicAdd(out + OUT_LOSS + b, lv * (1.0f / 1024.0f));
    }
}

// Epilogue 2: TAIL tokens only (region overlapping scratch), ALL 8 levels.
// Reads OUT_IDX floats (written by k_out1) — NOT idxws, which lies inside
// the region being overwritten.
__global__ __launch_bounds__(256) void k_out2(float* __restrict__ out,
                                              int tail0) {
    int tid = threadIdx.x;
    __shared__ int lidx[16][8];
    int tok0 = tail0 + blockIdx.x * 16;
    if (tid < 128) {
        int v = (int)out[OUT_IDX + tok0 * 8 + tid];
        lidx[tid >> 3][tid & 7] = v;
    }
    __syncthreads();
    f32x4* pb = (f32x4*)(out + OUT_PROBS) + (size_t)tok0 * 1024;
    for (int it = 0; it < 64; ++it) {
        int i = it * 256 + tid;
        int nl_ = i >> 10, l = (i >> 7) & 7, kg = i & 127;
        int rel = lidx[nl_][l] - kg * 4;
        f32x4 v;
        v[0] = (rel == 0) ? 1.0f : 0.0f;
        v[1] = (rel == 1) ? 1.0f : 0.0f;
        v[2] = (rel == 2) ? 1.0f : 0.0f;
        v[3] = (rel == 3) ? 1.0f : 0.0f;
        __builtin_nontemporal_store(v, pb + i);
    }
}

extern "C" void kernel_launch(void* const* d_in, const int* in_sizes, int n_in,
                              void* d_out, int out_size, void* d_ws, size_t ws_size,
                              hipStream_t stream) {
    const float* z = (const float*)d_in[0];
    const float* w = (const float*)d_in[1];
    float* out = (float*)d_out;

    float* sb = out + (out_size - SCR_FLOATS);
    f16* zh = (f16*)(sb + SF_ZH);
    f16* zl = (f16*)(sb + SF_ZL);
    f16* wh = (f16*)(sb + SF_WH);
    f16* wl = (f16*)(sb + SF_WL);
    float* b32 = (float*)(sb + SF_B32);
    float* g32 = (float*)(sb + SF_G32);
    double* G2 = (double*)(sb + SF_G2D);
    int* idxws = (int*)(sb + SF_IDX);
    int* idxL = (int*)(sb + SF_IDXL);
    float* klacc = (float*)(sb + SF_KL);
    int* done = (int*)(sb + SF_DONE);
    float* accS = (float*)(sb + SF_ACC);

    // Tokens whose probs slices lie entirely below the scratch tail get their
    // probs written during the level loop / k_out1. out_size=71,434,256 ->
    // n_safe=12986, tail0=12976, 213 tail blocks + 811 head(level-7) blocks.
    long scr_off = (long)out_size - SCR_FLOATS - OUT_PROBS;   // floats into probs
    int n_safe = (int)(scr_off >> 12);
    if (n_safe > 16384) n_safe = 16384;
    if (n_safe < 0) n_safe = 0;
    int tail0 = n_safe & ~15;
    int nblk_tail = (16384 - tail0) / 16;
    int nblk_head = tail0 / 16;
    int pgrid = (n_safe + 63) / 64;        // probs piggyback blocks per gsum

    k_prep<<<5392, 256, 0, stream>>>(z, w, zh, zl, wh, wl, b32, g32, G2,
                                     out + OUT_LOSS, done, accS);
    for (int l = 0; l < 8; ++l) {
        k_level<<<1024, 256, 0, stream>>>(z, w, accS, g32, G2, b32,
                                          idxws, idxL, klacc, l);
        if (l < 7)
            k_gsum<<<288 + pgrid, 256, 0, stream>>>(w, idxL, g32, G2, done,
                                                    out, accS, zh, zl, wh, wl,
                                                    n_safe, l);
    }
    k_out1<<<256 + nblk_head, 256, 0, stream>>>(w, b32, idxws, klacc, out, tail0);
    if (nblk_tail > 0)
        k_out2<<<nblk_tail, 256, 0, stream>>>(out, tail0);
}

// Round 13
// 1095.616 us; speedup vs baseline: 1.1168x; 1.1165x over previous
//
#include <hip/hip_runtime.h>

// HierarchicalResidualQuantizer on gfx950 — numpy-fp32-exact decision path.
// N=16384 tokens, D=256, L=8 levels, K=512 codes.
// Outputs (flat fp32 in d_out): q_out[16,256,32,32] @0, indices[16,32,32,8] @4194304,
// loss[16] @4325376, all_probs[16384,8,512] @4325392.  Total 71,434,256 floats.
// Scratch lives in the TAIL of the probs region.
//
// R20 (on R19's 1223; R17-R19 identical => serialized critical path is the cost):
// (1) DISTRIBUTED G2: the old single-block G2 tail (one CU, 131K scattered 4B
//     reads + 256-deep double-FMA chains, behind a device fence + done counter)
//     is replaced by per-chain-block partials: each of the 32 chain blocks
//     computes P_b[k] = sum_{d in its 8 dims} g_new[d]*w_{l+1}[k][d] and
//     unsafeAtomicAdd's 2*P_b into a double-buffered G2. G2 feeds only the
//     margin-protected approx path (mg ~1e-4); double-order change ~1e-16 rel.
//     Removes done counter, threadfences, and spin entirely.
//     k_level(l) block 0 zeroes the next G2 buffer (kernel-ordered, race-free).
// (2) Phase B 16-iter loop unrolled (load hoisting).
// Carried: Phase-A hoist via ACCS (T=64 tiled in gsum/prep), T=16 k_level grid
// 1024, gsum probs piggyback, merged prep, R13 epilogue ordering.

typedef _Float16 f16;
typedef _Float16 half8 __attribute__((ext_vector_type(8)));
typedef _Float16 half4v __attribute__((ext_vector_type(4)));
typedef float f32x4 __attribute__((ext_vector_type(4)));

#define LOGK 6.238324625039508f

#define OUT_IDX 4194304
#define OUT_LOSS 4325376
#define OUT_PROBS 4325392

#define SCR_FLOATS 13916432
// scratch offsets in floats
#define SF_ZH 0              // f16[16384*256] TILED z hi
#define SF_ZL 2097152        // f16[16384*256] TILED z lo
#define SF_WH 4194304        // f16[4096*256]  TILED w hi
#define SF_WL 4718592        // f16[4096*256]  TILED w lo
#define SF_B32 5242880       // float[4096]  fp32 pairwise ||w||^2 (numpy-exact)
#define SF_G32 5246976       // float[256]   fp32 global_sum (numpy-exact bits)
#define SF_G2D 5247232       // double[512]  G2 buffer A
#define SF_IDX 5248256       // int[16384*8]
#define SF_IDXL 5379328      // int[8*16384] level-major indices
#define SF_KL 5510400        // float[16384]
#define SF_ACC 5526800       // float[16384*512] Phase-A scores for current level
#define SF_G2B 13915408      // double[512]  G2 buffer B

// Tiled index: element (row16-group g16, lane-row lr, col d) with
// kx=d>>5, quad=(d>>3)&3, j=d&7 lives at ((g16*8+kx)*64 + quad*16+lr)*8 + j.

// ---------- numpy pairwise-128 block: 8 accumulators + fixed combine tree ----------
__device__ __forceinline__ float np_combine8(const float r[8]) {
    return __fadd_rn(__fadd_rn(__fadd_rn(r[0], r[1]), __fadd_rn(r[2], r[3])),
                     __fadd_rn(__fadd_rn(r[4], r[5]), __fadd_rn(r[6], r[7])));
}

// hi/lo fp16 split of 8 scaled floats — identical arithmetic to prep's split.
__device__ __forceinline__ void cvt8(const float* p, float sc, half8& h, half8& l) {
    #pragma unroll
    for (int j = 0; j < 8; ++j) {
        float v = p[j] * sc;
        f16 hh = (f16)v;
        h[j] = hh;
        l[j] = (f16)(v - (float)hh);
    }
}

// Phase A, T=64 tokens / 256 threads (4 waves), two code-passes of 256 codes,
// TILED fragment loads. MFMA order per (token,code): per k0 ascending,
// (hi*bh, hi*bl, lo*bh) — R8-exact; ACCS bit-identical.
__device__ __forceinline__ void phaseA64(
        int tid, int tok0, int lvl, float* __restrict__ accS,
        const f16* __restrict__ zt_h, const f16* __restrict__ zt_l,
        const f16* __restrict__ wt_h, const f16* __restrict__ wt_l) {
    const int wave = tid >> 6, lane = tid & 63;
    const int quad = lane >> 4, lr = lane & 15;
    const int g16b = tok0 >> 4;
    #pragma unroll
    for (int cp = 0; cp < 2; ++cp) {
        const int code0 = cp * 256 + wave * 64;
        const int c16b = lvl * 32 + (code0 >> 4);
        f32x4 acc[4][4];
        #pragma unroll
        for (int g = 0; g < 4; ++g)
            #pragma unroll
            for (int nt = 0; nt < 4; ++nt)
                acc[g][nt] = (f32x4){0.f, 0.f, 0.f, 0.f};
        for (int kx = 0; kx < 8; ++kx) {
            half8 ah[4], al[4];
            #pragma unroll
            for (int g = 0; g < 4; ++g) {
                int off = (((g16b + g) * 8 + kx) * 64 + lane) * 8;
                ah[g] = *(const half8*)(zt_h + off);
                al[g] = *(const half8*)(zt_l + off);
            }
            half8 bh[4], bl[4];
            #pragma unroll
            for (int nt = 0; nt < 4; ++nt) {
                int off = (((c16b + nt) * 8 + kx) * 64 + lane) * 8;
                bh[nt] = *(const half8*)(wt_h + off);
                bl[nt] = *(const half8*)(wt_l + off);
            }
            #pragma unroll
            for (int nt = 0; nt < 4; ++nt)
                #pragma unroll
                for (int g = 0; g < 4; ++g) {
                    acc[g][nt] = __builtin_amdgcn_mfma_f32_16x16x32_f16(ah[g], bh[nt], acc[g][nt], 0, 0, 0);
                    acc[g][nt] = __builtin_amdgcn_mfma_f32_16x16x32_f16(ah[g], bl[nt], acc[g][nt], 0, 0, 0);
                    acc[g][nt] = __builtin_amdgcn_mfma_f32_16x16x32_f16(al[g], bh[nt], acc[g][nt], 0, 0, 0);
                }
        }
        #pragma unroll
        for (int g = 0; g < 4; ++g)
            #pragma unroll
            for (int r = 0; r < 4; ++r) {
                int token = tok0 + g * 16 + quad * 4 + r;
                float* dst = accS + (size_t)token * 512 + code0 + lr;
                #pragma unroll
                for (int nt = 0; nt < 4; ++nt)
                    dst[nt * 16] = acc[g][nt][r];
            }
    }
}

// fp32-direct Phase A T=64 (level 0, inside prep): reads RAW z,w (identical
// split arithmetic, no dependency on the split blocks).
__device__ __forceinline__ void phaseA64_f32(
        int tid, int tok0, float* __restrict__ accS,
        const float* __restrict__ z, const float* __restrict__ w) {
    const int wave = tid >> 6, lane = tid & 63;
    const int quad = lane >> 4, lr = lane & 15;
    const float sc = 16.0f;                                    // 1<<(0+4)
    #pragma unroll
    for (int cp = 0; cp < 2; ++cp) {
        const int code0 = cp * 256 + wave * 64;
        const float* zr = z + (tok0 + lr) * 256 + quad * 8;
        const float* wr = w + (code0 + lr) * 256 + quad * 8;   // lvl 0
        f32x4 acc[4][4];
        #pragma unroll
        for (int g = 0; g < 4; ++g)
            #pragma unroll
            for (int nt = 0; nt < 4; ++nt)
                acc[g][nt] = (f32x4){0.f, 0.f, 0.f, 0.f};
        for (int k0 = 0; k0 < 256; k0 += 32) {
            half8 ah[4], al[4];
            #pragma unroll
            for (int g = 0; g < 4; ++g)
                cvt8(zr + g * 16 * 256 + k0, 1.0f, ah[g], al[g]);
            half8 bh[4], bl[4];
            #pragma unroll
            for (int nt = 0; nt < 4; ++nt)
                cvt8(wr + nt * 16 * 256 + k0, sc, bh[nt], bl[nt]);
            #pragma unroll
            for (int nt = 0; nt < 4; ++nt)
                #pragma unroll
                for (int g = 0; g < 4; ++g) {
                    acc[g][nt] = __builtin_amdgcn_mfma_f32_16x16x32_f16(ah[g], bh[nt], acc[g][nt], 0, 0, 0);
                    acc[g][nt] = __builtin_amdgcn_mfma_f32_16x16x32_f16(ah[g], bl[nt], acc[g][nt], 0, 0, 0);
                    acc[g][nt] = __builtin_amdgcn_mfma_f32_16x16x32_f16(al[g], bh[nt], acc[g][nt], 0, 0, 0);
                }
        }
        #pragma unroll
        for (int g = 0; g < 4; ++g)
            #pragma unroll
            for (int r = 0; r < 4; ++r) {
                int token = tok0 + g * 16 + quad * 4 + r;
                float* dst = accS + (size_t)token * 512 + code0 + lr;
                #pragma unroll
                for (int nt = 0; nt < 4; ++nt)
                    dst[nt * 16] = acc[g][nt][r];
            }
    }
}

// Fused prep: [0,4096) z hi/lo split -> TILED, [4096,5120) w hi/lo split ->
// TILED, [5120,5136) ||w||^2 + misc init (G2A zero), [5136,5392) Phase A lvl 0.
__global__ __launch_bounds__(256) void k_prep(
        const float* __restrict__ z, const float* __restrict__ w,
        f16* __restrict__ zh, f16* __restrict__ zl,
        f16* __restrict__ wh, f16* __restrict__ wl,
        float* __restrict__ b32, float* __restrict__ g32,
        double* __restrict__ G2A, float* __restrict__ loss_out,
        float* __restrict__ accS) {
    const int bid = blockIdx.x;
    const int tid = threadIdx.x;
    if (bid < 4096) {
        int i = (bid * 256 + tid) * 4;
        int n = i >> 8, d = i & 255;
        float4 v = *(const float4*)(z + i);
        half4v h, l;
        float c0 = v.x, c1 = v.y, c2 = v.z, c3 = v.w;
        f16 h0 = (f16)c0, h1 = (f16)c1, h2 = (f16)c2, h3 = (f16)c3;
        h[0] = h0; h[1] = h1; h[2] = h2; h[3] = h3;
        l[0] = (f16)(c0 - (float)h0); l[1] = (f16)(c1 - (float)h1);
        l[2] = (f16)(c2 - (float)h2); l[3] = (f16)(c3 - (float)h3);
        int g16 = n >> 4, lr = n & 15;
        int kx = d >> 5, quad = (d >> 3) & 3, j = d & 7;   // j in {0,4}
        int dst = ((g16 * 8 + kx) * 64 + quad * 16 + lr) * 8 + j;
        *(half4v*)(zh + dst) = h;
        *(half4v*)(zl + dst) = l;
    } else if (bid < 5120) {
        int row = (bid - 4096) * 4 + (tid >> 6);
        int lane = tid & 63;
        int lvl = row >> 9;
        int code_in = row & 511;
        float sc = (float)(1 << (lvl + 4));
        const float* wr = w + row * 256;
        int d0 = lane * 4;
        float4 v = *(const float4*)(wr + d0);
        half4v h, l;
        float s0 = v.x * sc, s1 = v.y * sc, s2 = v.z * sc, s3 = v.w * sc;
        f16 h0 = (f16)s0, h1 = (f16)s1, h2 = (f16)s2, h3 = (f16)s3;
        h[0] = h0; h[1] = h1; h[2] = h2; h[3] = h3;
        l[0] = (f16)(s0 - (float)h0); l[1] = (f16)(s1 - (float)h1);
        l[2] = (f16)(s2 - (float)h2); l[3] = (f16)(s3 - (float)h3);
        int c16 = code_in >> 4, lr = code_in & 15;
        int kx = d0 >> 5, quad = (d0 >> 3) & 3, j = d0 & 7;
        int dst = (((lvl * 32 + c16) * 8 + kx) * 64 + quad * 16 + lr) * 8 + j;
        *(half4v*)(wh + dst) = h;
        *(half4v*)(wl + dst) = l;
    } else if (bid < 5136) {
        int b = bid - 5120;                 // 0..15
        int row = b * 256 + tid;            // 0..4095
        const float* wr = w + row * 256;
        float res[2];
        #pragma unroll
        for (int h = 0; h < 2; ++h) {
            const float* x = wr + h * 128;
            float r[8];
            #pragma unroll
            for (int j = 0; j < 8; ++j) r[j] = __fmul_rn(x[j], x[j]);
            for (int i = 8; i < 128; i += 8)
                #pragma unroll
                for (int j = 0; j < 8; ++j) r[j] = __fadd_rn(r[j], __fmul_rn(x[i + j], x[i + j]));
            res[h] = np_combine8(r);
        }
        b32[row] = __fadd_rn(res[0], res[1]);
        if (b == 0) {
            g32[tid] = 0.0f;
            G2A[tid] = 0.0; G2A[tid + 256] = 0.0;
            if (tid < 16) loss_out[tid] = 0.0f;
        }
    } else {
        int tok0 = (bid - 5136) * 64;
        phaseA64_f32(tid, tok0, accS, z, w);
    }
}

// Per-level, 16 tokens/block, 256 threads, grid 1024 (4 blocks/CU).
// Phase A is PRE-COMPUTED in ACCS. Block 0 additionally zeroes G2next (for
// gsum(l)'s distributed partials; kernel-ordered, race-free).
__global__ __launch_bounds__(256, 4) void k_level(
        const float* __restrict__ zf, const float* __restrict__ wf,
        const float* __restrict__ accS,
        const float* __restrict__ g32, const double* __restrict__ G2,
        double* __restrict__ G2n,
        const float* __restrict__ b32,
        int* __restrict__ idxws, int* __restrict__ idxL,
        float* __restrict__ klacc, int lvl) {
    __shared__ float bS[512];
    __shared__ float g2S[512];
    __shared__ float gS[256];
    __shared__ float pb[16][16];
    __shared__ float aS[16], mgS[16];
    __shared__ unsigned short cand[16][256];
    __shared__ int ccnt[16];
    __shared__ int bidxS[16];

    const int tid = threadIdx.x;
    const int tok0 = blockIdx.x * 16;

    if (blockIdx.x == 0) {             // zero next-level G2 buffer
        G2n[tid] = 0.0;
        G2n[tid + 256] = 0.0;
    }

    // stage
    gS[tid] = g32[tid & 255];
    bS[tid] = b32[lvl * 512 + tid]; bS[tid + 256] = b32[lvl * 512 + tid + 256];
    g2S[tid] = (float)G2[tid]; g2S[tid + 256] = (float)G2[tid + 256];
    if (tid < 16) ccnt[tid] = 0;
    __syncthreads();

    // Phase B: a_n = numpy-pairwise fp32 sum of resid^2 (16 threads/token,
    // R12-validated (t,h,s) split — chains bit-identical to R8; unrolled so
    // the 16 loads hoist above the dependent chain).
    {
        int t = tid >> 4, s5 = tid & 15, h = s5 >> 3, s = s5 & 7;
        const float* zr = zf + (tok0 + t) * 256;
        int base = h * 128 + s;
        float x0 = __fsub_rn(zr[base], gS[base]);
        float r = __fmul_rn(x0, x0);
        #pragma unroll
        for (int i = 1; i < 16; ++i) {
            float xv = __fsub_rn(zr[base + i * 8], gS[base + i * 8]);
            r = __fadd_rn(r, __fmul_rn(xv, xv));
        }
        pb[t][h * 8 + s] = r;
    }
    __syncthreads();
    if (tid < 16) {
        float r0[8], r1[8];
        #pragma unroll
        for (int j = 0; j < 8; ++j) { r0[j] = pb[tid][j]; r1[j] = pb[tid][8 + j]; }
        float a = __fadd_rn(np_combine8(r0), np_combine8(r1));
        aS[tid] = a;
        unsigned e = (__float_as_uint(a) >> 23) & 0xffu;
        float ulp = __uint_as_float((e - 23u) << 23);
        mgS[tid] = 2.5f * ulp + 1e-4f * sqrtf(a) / (float)(1 << lvl) + 1e-6f;
    }
    __syncthreads();

    // Phase C/C2: thread (t = tid>>4, s = tid&15) owns codes [s*32, s*32+32)
    // of token t. D bit-identical; Dmax/cand-set order-free; KL order change
    // covered by loss slack 10.24.
    const float inv2f = 1.0f / (float)(1 << (lvl + 3));
    {
        int t = tid >> 4, s = tid & 15;
        const f32x4* ar = (const f32x4*)(accS + (size_t)(tok0 + t) * 512 + s * 32);
        f32x4 Dv[8];
        #pragma unroll
        for (int j = 0; j < 8; ++j) Dv[j] = ar[j];
        float aT = aS[t];
        float m = -3.4e38f;
        #pragma unroll
        for (int j = 0; j < 8; ++j) {
            #pragma unroll
            for (int e = 0; e < 4; ++e) {
                int code = s * 32 + j * 4 + e;
                float c2 = __fsub_rn(__fmul_rn(Dv[j][e], inv2f), g2S[code]);
                float D = -__fsub_rn(__fadd_rn(aT, bS[code]), c2);
                Dv[j][e] = D;
                m = fmaxf(m, D);
            }
        }
        #pragma unroll
        for (int msk = 1; msk < 16; msk <<= 1) m = fmaxf(m, __shfl_xor(m, msk));
        float Dm = m, mg = mgS[t];
        float se = 0.f, sd = 0.f;
        #pragma unroll
        for (int j = 0; j < 8; ++j) {
            #pragma unroll
            for (int e = 0; e < 4; ++e) {
                float D = Dv[j][e];
                float d = Dm - D;
                se += __expf(-d);
                sd += d;
                if (D >= Dm - mg) {
                    int pos = atomicAdd(&ccnt[t], 1);
                    if (pos < 256) cand[t][pos] = (unsigned short)(s * 32 + j * 4 + e);
                }
            }
        }
        #pragma unroll
        for (int msk = 1; msk < 16; msk <<= 1) {
            se += __shfl_xor(se, msk);
            sd += __shfl_xor(sd, msk);
        }
        if (s == 0) {
            float kl = __logf(se) + sd * (1.0f / 512.0f) - LOGK;
            int n = tok0 + t;
            float prev = (lvl == 0) ? 0.0f : klacc[n];
            klacc[n] = prev + 0.1f * kl;
        }
    }
    __syncthreads();

    // Phase E: exact numpy-fp32 dist for candidates. float4 loads, 16-elem
    // groups, unroll 2. fmaf order over j=0..255 identical to scalar loop.
    {
        int t = tid >> 4, s = tid & 15;
        int n = tok0 + t;
        const float4* zr4 = (const float4*)(zf + n * 256);
        int cnt = ccnt[t]; if (cnt > 256) cnt = 256;
        float aT = aS[t];
        float bD = -3.4e38f; int bI = 0x7fffffff;
        for (int ci = s; ci < cnt; ci += 16) {
            int code = cand[t][ci];
            const float4* wr4 = (const float4*)(wf + (lvl * 512 + code) * 256);
            float c = 0.f;
            #pragma unroll 2
            for (int gq = 0; gq < 16; ++gq) {
                float4 w0 = wr4[gq * 4 + 0], w1 = wr4[gq * 4 + 1];
                float4 w2 = wr4[gq * 4 + 2], w3 = wr4[gq * 4 + 3];
                float4 z0 = zr4[gq * 4 + 0], z1 = zr4[gq * 4 + 1];
                float4 z2 = zr4[gq * 4 + 2], z3 = zr4[gq * 4 + 3];
                int b0 = gq * 16;
                c = fmaf(__fsub_rn(z0.x, gS[b0 + 0]), w0.x, c);
                c = fmaf(__fsub_rn(z0.y, gS[b0 + 1]), w0.y, c);
                c = fmaf(__fsub_rn(z0.z, gS[b0 + 2]), w0.z, c);
                c = fmaf(__fsub_rn(z0.w, gS[b0 + 3]), w0.w, c);
                c = fmaf(__fsub_rn(z1.x, gS[b0 + 4]), w1.x, c);
                c = fmaf(__fsub_rn(z1.y, gS[b0 + 5]), w1.y, c);
                c = fmaf(__fsub_rn(z1.z, gS[b0 + 6]), w1.z, c);
                c = fmaf(__fsub_rn(z1.w, gS[b0 + 7]), w1.w, c);
                c = fmaf(__fsub_rn(z2.x, gS[b0 + 8]), w2.x, c);
                c = fmaf(__fsub_rn(z2.y, gS[b0 + 9]), w2.y, c);
                c = fmaf(__fsub_rn(z2.z, gS[b0 + 10]), w2.z, c);
                c = fmaf(__fsub_rn(z2.w, gS[b0 + 11]), w2.w, c);
                c = fmaf(__fsub_rn(z3.x, gS[b0 + 12]), w3.x, c);
                c = fmaf(__fsub_rn(z3.y, gS[b0 + 13]), w3.y, c);
                c = fmaf(__fsub_rn(z3.z, gS[b0 + 14]), w3.z, c);
                c = fmaf(__fsub_rn(z3.w, gS[b0 + 15]), w3.w, c);
            }
            float D = -__fsub_rn(__fadd_rn(aT, bS[code]), __fadd_rn(c, c));
            if (D > bD || (D == bD && code < bI)) { bD = D; bI = code; }
        }
        #pragma unroll
        for (int msk = 1; msk < 16; msk <<= 1) {
            float oD = __shfl_xor(bD, msk);
            int oI = __shfl_xor(bI, msk);
            if (oD > bD || (oD == bD && oI < bI)) { bD = oD; bI = oI; }
        }
        if (s == 0) bidxS[t] = bI;
    }
    __syncthreads();
    if (tid < 16) {
        int gi = bidxS[tid];
        int n = tok0 + tid;
        idxws[n * 8 + lvl] = gi;
        idxL[lvl * 16384 + n] = gi;
    }
}

// g update + distributed G2 + hidden work. Blocks [0,32): chain (8 dims each,
// R11-verbatim order) + per-block G2 partial into G2n (double atomics).
// Blocks [32,288): Phase A for level lvl+1 into ACCS (T=64, tiled loads).
// Blocks [288,...): probs piggyback for level lvl, n < n_safe.
__global__ __launch_bounds__(256) void k_gsum(const float* __restrict__ w,
        const int* __restrict__ idxL, float* __restrict__ g32,
        double* __restrict__ G2n,
        float* __restrict__ outp, float* __restrict__ accS,
        const f16* __restrict__ zh, const f16* __restrict__ zl,
        const f16* __restrict__ wh, const f16* __restrict__ wl,
        int n_safe, int lvl) {
    const int tid = threadIdx.x;
    if (blockIdx.x >= 288) {
        __shared__ int li[64];
        int tok0 = ((int)blockIdx.x - 288) * 64;
        if (tid < 64) {
            int n = tok0 + tid;
            li[tid] = (n < n_safe) ? idxL[lvl * 16384 + n] : 0;
        }
        __syncthreads();
        f32x4* pb4 = (f32x4*)(outp + OUT_PROBS);
        #pragma unroll
        for (int it = 0; it < 32; ++it) {
            int i = it * 256 + tid;           // 0..8191
            int t = i >> 7, kg = i & 127;
            int n = tok0 + t;
            if (n < n_safe) {
                int rel = li[t] - kg * 4;
                f32x4 v;
                v[0] = (rel == 0) ? 1.0f : 0.0f;
                v[1] = (rel == 1) ? 1.0f : 0.0f;
                v[2] = (rel == 2) ? 1.0f : 0.0f;
                v[3] = (rel == 3) ? 1.0f : 0.0f;
                __builtin_nontemporal_store(v, pb4 + ((size_t)n * 1024 + lvl * 128 + kg));
            }
        }
        return;
    }
    if (blockIdx.x >= 32) {
        // Phase A for level lvl+1 (lvl<7 always here), T=64, tiled loads.
        int tok0 = ((int)blockIdx.x - 32) * 64;
        phaseA64(tid, tok0, lvl + 1, accS, zh, zl, wh, wl);
        return;
    }
    __shared__ float wcol[512 * 13];       // [code][dim(8), stride 13]
    __shared__ float vals[2][8][520];      // [buf][dim][token-in-chunk]
    __shared__ float gnewS[8];
    const int d0 = blockIdx.x * 8;
    {   // stage the 512x8 column slice
        const float* wb = w + lvl * 131072 + d0;
        for (int i = tid; i < 4096; i += 256)
            wcol[(i >> 3) * 13 + (i & 7)] = wb[(i >> 3) * 256 + (i & 7)];
    }
    const int* __restrict__ codes = idxL + lvl * 16384;
    const bool producer = (tid < 192);
    const int cl = tid - 248;              // consumer lane 0..7 when >= 0
    if (producer) {
        for (int k = tid; k < 512; k += 192) {
            int c = codes[k] * 13;
            float v0 = wcol[c], v1 = wcol[c + 1], v2 = wcol[c + 2], v3 = wcol[c + 3];
            float v4 = wcol[c + 4], v5 = wcol[c + 5], v6 = wcol[c + 6], v7 = wcol[c + 7];
            vals[0][0][k] = v0; vals[0][1][k] = v1; vals[0][2][k] = v2; vals[0][3][k] = v3;
            vals[0][4][k] = v4; vals[0][5][k] = v5; vals[0][6][k] = v6; vals[0][7][k] = v7;
        }
    }
    __syncthreads();
    float acc = 0.f;
    for (int ch = 0; ch < 32; ++ch) {
        const int cb = ch & 1, nb = cb ^ 1;
        if (producer) {
            if (ch < 31) {
                int base = (ch + 1) << 9;
                for (int k = tid; k < 512; k += 192) {
                    int c = codes[base + k] * 13;
                    float v0 = wcol[c], v1 = wcol[c + 1], v2 = wcol[c + 2], v3 = wcol[c + 3];
                    float v4 = wcol[c + 4], v5 = wcol[c + 5], v6 = wcol[c + 6], v7 = wcol[c + 7];
                    vals[nb][0][k] = v0; vals[nb][1][k] = v1; vals[nb][2][k] = v2; vals[nb][3][k] = v3;
                    vals[nb][4][k] = v4; vals[nb][5][k] = v5; vals[nb][6][k] = v6; vals[nb][7][k] = v7;
                }
            }
        } else if (cl >= 0) {
            const float4* vp = (const float4*)(&vals[cb][cl][0]);  // 128 float4
            float4 A[16], B[16];
            #pragma unroll
            for (int j = 0; j < 16; ++j) A[j] = vp[j];
            #pragma unroll
            for (int s = 0; s < 8; ++s) {
                if ((s & 1) == 0) {
                    if (s < 7) {
                        #pragma unroll
                        for (int j = 0; j < 16; ++j) B[j] = vp[(s + 1) * 16 + j];
                    }
                    #pragma unroll
                    for (int j = 0; j < 16; ++j) {
                        acc = __fadd_rn(acc, A[j].x);
                        acc = __fadd_rn(acc, A[j].y);
                        acc = __fadd_rn(acc, A[j].z);
                        acc = __fadd_rn(acc, A[j].w);
                    }
                } else {
                    if (s < 7) {
                        #pragma unroll
                        for (int j = 0; j < 16; ++j) A[j] = vp[(s + 1) * 16 + j];
                    }
                    #pragma unroll
                    for (int j = 0; j < 16; ++j) {
                        acc = __fadd_rn(acc, B[j].x);
                        acc = __fadd_rn(acc, B[j].y);
                        acc = __fadd_rn(acc, B[j].z);
                        acc = __fadd_rn(acc, B[j].w);
                    }
                }
            }
        }
        __syncthreads();
    }
    if (cl >= 0) {
        float gn = __fadd_rn(g32[d0 + cl], acc);
        g32[d0 + cl] = gn;
        gnewS[cl] = gn;
    }
    __syncthreads();
    // Distributed G2 partial for level lvl+1: this block's 8 dims x all 512
    // codes; double atomics into the (k_level-zeroed) next G2 buffer.
    {
        const float* wn = w + (lvl + 1) * 131072 + d0;
        for (int k = tid; k < 512; k += 256) {
            const float* wr = wn + k * 256;
            double P = 0.0;
            #pragma unroll
            for (int d = 0; d < 8; ++d)
                P = fma((double)gnewS[d], (double)wr[d], P);
            unsafeAtomicAdd(&G2n[k], 2.0 * P);
        }
    }
}

// Merged epilogue 1. Blocks [0,256): q_out (float4 gather) + indices + loss.
// Blocks [256, 256+nblk_head): level-7 one-hot probs for HEAD tokens (safe
// region only).
__global__ __launch_bounds__(256) void k_out1(const float* __restrict__ w,
        const float* __restrict__ b32, const int* __restrict__ idxws,
        const float* __restrict__ klacc, float* __restrict__ out, int tail0) {
    int tid = threadIdx.x;
    if (blockIdx.x >= 256) {
        __shared__ int l7[16];
        int tok0 = ((int)blockIdx.x - 256) * 16;
        if (tok0 >= tail0) return;
        if (tid < 16) l7[tid] = idxws[(tok0 + tid) * 8 + 7];
        __syncthreads();
        f32x4* pb = (f32x4*)(out + OUT_PROBS);
        #pragma unroll
        for (int it = 0; it < 8; ++it) {
            int i = it * 256 + tid;           // 0..2047
            int t = i >> 7, kg = i & 127;
            int rel = l7[t] - kg * 4;
            f32x4 v;
            v[0] = (rel == 0) ? 1.0f : 0.0f;
            v[1] = (rel == 1) ? 1.0f : 0.0f;
            v[2] = (rel == 2) ? 1.0f : 0.0f;
            v[3] = (rel == 3) ? 1.0f : 0.0f;
            __builtin_nontemporal_store(v, pb + (size_t)(tok0 + t) * 1024 + 7 * 128 + kg);
        }
        return;
    }
    __shared__ int lidx[64][8];
    int tok0 = blockIdx.x * 64;
    int b = tok0 >> 10, hw0 = tok0 & 1023;

    for (int s = tid; s < 512; s += 256) {
        int v = idxws[tok0 * 8 + s];
        lidx[s >> 3][s & 7] = v;
        out[OUT_IDX + tok0 * 8 + s] = (float)v;
    }
    __syncthreads();

    {
        int j = tid & 63, q = tid >> 6;
        int id[8];
        #pragma unroll
        for (int l = 0; l < 8; ++l) id[l] = lidx[j][l];
        for (int dd = 0; dd < 64; dd += 4) {
            int d = q * 64 + dd;
            float s0 = 0.f, s1 = 0.f, s2 = 0.f, s3 = 0.f;
            #pragma unroll
            for (int l = 0; l < 8; ++l) {
                float4 wv = *(const float4*)(w + l * 131072 + id[l] * 256 + d);
                s0 += wv.x; s1 += wv.y; s2 += wv.z; s3 += wv.w;
            }
            float* ob = out + b * 262144 + d * 1024 + hw0 + j;
            ob[0] = s0; ob[1024] = s1; ob[2048] = s2; ob[3072] = s3;
        }
    }

    if (tid < 64) {
        int n = tok0 + tid;
        float lv = klacc[n];
        float nl = 0.f;
        #pragma unroll
        for (int jj = 0; jj < 7; ++jj) {
            float up = sqrtf(b32[jj * 512 + lidx[tid][jj]]);
            float lo = sqrtf(b32[(jj + 1) * 512 + lidx[tid][jj + 1]]);
            float ratio = 4.0f * (lo / up);
            float m = fmaxf(ratio, 1.0f) - 1.0f;
            nl += m * m;
        }
        lv += nl * (1.0f / 7.0f) * 0.1f;
        #pragma unroll
        for (int msk = 1; msk < 64; msk <<= 1) lv += __shfl_xor(lv, msk);
        if (tid == 0) atomicAdd(out + OUT_LOSS + b, lv * (1.0f / 1024.0f));
    }
}

// Epilogue 2: TAIL tokens only (region overlapping scratch), ALL 8 levels.
// Reads OUT_IDX floats (written by k_out1) — NOT idxws (inside overwrite zone).
__global__ __launch_bounds__(256) void k_out2(float* __restrict__ out,
                                              int tail0) {
    int tid = threadIdx.x;
    __shared__ int lidx[16][8];
    int tok0 = tail0 + blockIdx.x * 16;
    if (tid < 128) {
        int v = (int)out[OUT_IDX + tok0 * 8 + tid];
        lidx[tid >> 3][tid & 7] = v;
    }
    __syncthreads();
    f32x4* pb = (f32x4*)(out + OUT_PROBS) + (size_t)tok0 * 1024;
    for (int it = 0; it < 64; ++it) {
        int i = it * 256 + tid;
        int nl_ = i >> 10, l = (i >> 7) & 7, kg = i & 127;
        int rel = lidx[nl_][l] - kg * 4;
        f32x4 v;
        v[0] = (rel == 0) ? 1.0f : 0.0f;
        v[1] = (rel == 1) ? 1.0f : 0.0f;
        v[2] = (rel == 2) ? 1.0f : 0.0f;
        v[3] = (rel == 3) ? 1.0f : 0.0f;
        __builtin_nontemporal_store(v, pb + i);
    }
}

extern "C" void kernel_launch(void* const* d_in, const int* in_sizes, int n_in,
                              void* d_out, int out_size, void* d_ws, size_t ws_size,
                              hipStream_t stream) {
    const float* z = (const float*)d_in[0];
    const float* w = (const float*)d_in[1];
    float* out = (float*)d_out;

    float* sb = out + (out_size - SCR_FLOATS);
    f16* zh = (f16*)(sb + SF_ZH);
    f16* zl = (f16*)(sb + SF_ZL);
    f16* wh = (f16*)(sb + SF_WH);
    f16* wl = (f16*)(sb + SF_WL);
    float* b32 = (float*)(sb + SF_B32);
    float* g32 = (float*)(sb + SF_G32);
    double* G2A = (double*)(sb + SF_G2D);
    double* G2B = (double*)(sb + SF_G2B);
    int* idxws = (int*)(sb + SF_IDX);
    int* idxL = (int*)(sb + SF_IDXL);
    float* klacc = (float*)(sb + SF_KL);
    float* accS = (float*)(sb + SF_ACC);

    // Tokens whose probs slices lie entirely below the scratch tail get their
    // probs written during the level loop / k_out1.
    long scr_off = (long)out_size - SCR_FLOATS - OUT_PROBS;   // floats into probs
    int n_safe = (int)(scr_off >> 12);
    if (n_safe > 16384) n_safe = 16384;
    if (n_safe < 0) n_safe = 0;
    int tail0 = n_safe & ~15;
    int nblk_tail = (16384 - tail0) / 16;
    int nblk_head = tail0 / 16;
    int pgrid = (n_safe + 63) / 64;        // probs piggyback blocks per gsum

    k_prep<<<5392, 256, 0, stream>>>(z, w, zh, zl, wh, wl, b32, g32, G2A,
                                     out + OUT_LOSS, accS);
    for (int l = 0; l < 8; ++l) {
        double* cur = (l & 1) ? G2B : G2A;
        double* nxt = (l & 1) ? G2A : G2B;
        k_level<<<1024, 256, 0, stream>>>(z, w, accS, g32, cur, nxt, b32,
                                          idxws, idxL, klacc, l);
        if (l < 7)
            k_gsum<<<288 + pgrid, 256, 0, stream>>>(w, idxL, g32, nxt,
                                                    out, accS, zh, zl, wh, wl,
                                                    n_safe, l);
    }
    k_out1<<<256 + nblk_head, 256, 0, stream>>>(w, b32, idxws, klacc, out, tail0);
    if (nblk_tail > 0)
        k_out2<<<nblk_tail, 256, 0, stream>>>(out, tail0);
}